// Round 1
// baseline (4421.428 us; speedup 1.0000x reference)
//
#include <hip/hip_runtime.h>
#include <hip/hip_bf16.h>

// DeepGCN forward: BN -> fc_in -> 4x[GEMM -> SpMM -> PairNorm -> ReLU -> residual] -> fc_out
// fp32 throughout. CSR built on-device once per launch (edges constant across layers).

constexpr int DD = 128;

struct alignas(16) f4 { float v[4]; };

// ---------------- column reduce: per-block partial colsum/colsumsq ----------------
__global__ __launch_bounds__(256) void col_reduce_k(const float* __restrict__ X, int n,
    float* __restrict__ psum, float* __restrict__ psq)
{
    int c = threadIdx.x & (DD - 1);
    int half = threadIdx.x >> 7;
    int rows_per_blk = (n + gridDim.x - 1) / gridDim.x;
    int r0 = blockIdx.x * rows_per_blk;
    int r1 = min(n, r0 + rows_per_blk);
    float s = 0.f, ss = 0.f;
    for (int r = r0 + half; r < r1; r += 2) {
        float v = X[(size_t)r * DD + c];
        s += v; ss += v * v;
    }
    __shared__ float ls[256], lq[256];
    ls[threadIdx.x] = s; lq[threadIdx.x] = ss;
    __syncthreads();
    if (half == 0) {
        psum[blockIdx.x * DD + c] = ls[c] + ls[c + 128];
        psq [blockIdx.x * DD + c] = lq[c] + lq[c + 128];
    }
}

// ---------------- BN finalize: A = gamma*rstd, B = beta - mu*A ----------------
__global__ void bn_finalize_k(const float* __restrict__ psum, const float* __restrict__ psq,
    int nblk, int n, const float* __restrict__ gamma, const float* __restrict__ beta,
    float* __restrict__ AB)
{
    int c = threadIdx.x;  // 128 threads
    float s = 0.f, ss = 0.f;
    for (int b = 0; b < nblk; b++) { s += psum[b * DD + c]; ss += psq[b * DD + c]; }
    float mu = s / (float)n;
    float var = ss / (float)n - mu * mu;
    float a = gamma[c] * rsqrtf(var + 1e-5f);
    AB[c] = a;
    AB[DD + c] = beta[c] - mu * a;
}

// ---------------- PairNorm finalize: A = inv_rn, B = -mu*inv_rn ----------------
__global__ void pn_finalize_k(const float* __restrict__ psum, const float* __restrict__ psq,
    int nblk, int n, float* __restrict__ AB)
{
    int c = threadIdx.x;  // 128 threads
    float s = 0.f, ss = 0.f;
    for (int b = 0; b < nblk; b++) { s += psum[b * DD + c]; ss += psq[b * DD + c]; }
    float mu = s / (float)n;
    float cent = ss - (float)n * mu * mu;   // per-col centered sumsq
    __shared__ float red[DD];
    red[c] = cent;
    __syncthreads();
    for (int off = 64; off > 0; off >>= 1) {
        if (c < off) red[c] += red[c + off];
        __syncthreads();
    }
    float inv = rsqrtf(1e-6f + red[0] / (float)n);
    AB[c] = inv;
    AB[DD + c] = -mu * inv;
}

// ---------------- GEMM: Y[n,NCOL] = X[n,128] @ W[128,NCOL] (+bias) ----------------
// INSCALE: apply x*A[k]+B[k] per input column while staging (fused BatchNorm).
template<int NCOL, bool INSCALE, bool BIAS>
__global__ __launch_bounds__(256) void gemm_k128(const float* __restrict__ X,
    const float* __restrict__ W, const float* __restrict__ bias,
    const float* __restrict__ AB, float* __restrict__ Y, int n)
{
    __shared__ float xs[32][DD];
    __shared__ float ws[DD][NCOL];
    const int t = threadIdx.x;

    // stage W (full) into LDS
    {
        const f4* Wv = reinterpret_cast<const f4*>(W);
        f4* wsv = reinterpret_cast<f4*>(&ws[0][0]);
        for (int i = t; i < DD * NCOL / 4; i += 256) wsv[i] = Wv[i];
    }
    // stage X tile (32 rows)
    const int row0 = blockIdx.x * 32;
    for (int i = t; i < 32 * DD / 4; i += 256) {
        int r = i >> 5;
        int k = (i & 31) << 2;
        f4 v; v.v[0] = v.v[1] = v.v[2] = v.v[3] = 0.f;
        if (row0 + r < n) v = *reinterpret_cast<const f4*>(X + (size_t)(row0 + r) * DD + k);
        if (INSCALE) {
            #pragma unroll
            for (int j = 0; j < 4; j++) v.v[j] = v.v[j] * AB[k + j] + AB[DD + k + j];
        }
        *reinterpret_cast<f4*>(&xs[r][k]) = v;
    }
    __syncthreads();

    constexpr int TC = (NCOL >= 128) ? 32 : 16;  // col groups of 4
    constexpr int TR = 256 / TC;                 // row groups
    constexpr int RPT = 32 / TR;                 // rows per thread
    const int tc = t % TC, tr = t / TC;
    const int c0 = tc * 4;
    const int r0 = tr * RPT;
    if (c0 < NCOL) {
        float acc[RPT][4];
        #pragma unroll
        for (int i = 0; i < RPT; i++)
            #pragma unroll
            for (int j = 0; j < 4; j++) acc[i][j] = 0.f;

        #pragma unroll
        for (int k0 = 0; k0 < DD; k0 += 4) {
            f4 a[RPT], w[4];
            #pragma unroll
            for (int i = 0; i < RPT; i++) a[i] = *reinterpret_cast<const f4*>(&xs[r0 + i][k0]);
            #pragma unroll
            for (int q = 0; q < 4; q++) w[q] = *reinterpret_cast<const f4*>(&ws[k0 + q][c0]);
            #pragma unroll
            for (int i = 0; i < RPT; i++)
                #pragma unroll
                for (int q = 0; q < 4; q++)
                    #pragma unroll
                    for (int j = 0; j < 4; j++)
                        acc[i][j] = fmaf(a[i].v[q], w[q].v[j], acc[i][j]);
        }

        #pragma unroll
        for (int i = 0; i < RPT; i++) {
            int r = row0 + r0 + i;
            if (r < n) {
                f4 o;
                #pragma unroll
                for (int j = 0; j < 4; j++) o.v[j] = acc[i][j] + (BIAS ? bias[c0 + j] : 0.f);
                *reinterpret_cast<f4*>(Y + (size_t)r * NCOL + c0) = o;
            }
        }
    }
}

// ---------------- CSR build ----------------
__global__ __launch_bounds__(256) void hist_k(const int* __restrict__ erow,
    int* __restrict__ deg, int e)
{
    int i = blockIdx.x * 256 + threadIdx.x;
    if (i < e) atomicAdd(&deg[erow[i]], 1);
}

__global__ __launch_bounds__(1024) void scan_k(const int* __restrict__ deg,
    int* __restrict__ rowptr, int* __restrict__ cursor, int n)
{
    const int T = 1024;
    int t = threadIdx.x;
    int chunk = (n + T - 1) / T;
    int lo = min(n, t * chunk), hi = min(n, lo + chunk);
    int s = 0;
    for (int i = lo; i < hi; i++) s += deg[i];
    __shared__ int ps[T];
    ps[t] = s;
    __syncthreads();
    for (int off = 1; off < T; off <<= 1) {
        int add = (t >= off) ? ps[t - off] : 0;
        __syncthreads();
        ps[t] += add;
        __syncthreads();
    }
    int run = (t > 0) ? ps[t - 1] : 0;
    for (int i = lo; i < hi; i++) {
        int d = deg[i];
        rowptr[i] = run;
        cursor[i] = run;
        run += d;
    }
    if (t == T - 1) rowptr[n] = ps[T - 1];
}

__global__ __launch_bounds__(256) void scatter_k(const int* __restrict__ erow,
    const int* __restrict__ ecol, const float* __restrict__ evalv,
    int* __restrict__ cursor, int* __restrict__ ccol, float* __restrict__ cval, int e)
{
    int i = blockIdx.x * 256 + threadIdx.x;
    if (i >= e) return;
    int r = erow[i];
    int p = atomicAdd(&cursor[r], 1);
    ccol[p] = ecol[i];
    cval[p] = evalv[i];
}

// ---------------- SpMM (CSR gather): AGG[r,:] = sum_e val*H[col,:] ----------------
__global__ __launch_bounds__(256) void spmm_csr_k(const int* __restrict__ rowptr,
    const int* __restrict__ ccol, const float* __restrict__ cval,
    const float* __restrict__ H, float* __restrict__ AGG, int n)
{
    int g = blockIdx.x * 256 + threadIdx.x;
    int r = g >> 5;          // 32 threads per row
    int lane = g & 31;       // 4 floats each
    if (r >= n) return;
    int p0 = rowptr[r], p1 = rowptr[r + 1];
    float ax = 0.f, ay = 0.f, az = 0.f, aw = 0.f;
    for (int p = p0; p < p1; p++) {
        int c = ccol[p];
        float v = cval[p];
        const f4 h = *reinterpret_cast<const f4*>(H + (size_t)c * DD + lane * 4);
        ax = fmaf(v, h.v[0], ax);
        ay = fmaf(v, h.v[1], ay);
        az = fmaf(v, h.v[2], az);
        aw = fmaf(v, h.v[3], aw);
    }
    f4 o; o.v[0] = ax; o.v[1] = ay; o.v[2] = az; o.v[3] = aw;
    *reinterpret_cast<f4*>(AGG + (size_t)r * DD + lane * 4) = o;
}

// ---------------- PairNorm apply + ReLU + residual (in place on X) ----------------
__global__ __launch_bounds__(256) void pn_apply_k(const float* __restrict__ AGG,
    const float* __restrict__ AB, float* __restrict__ Xio, int total4, int add_old)
{
    int idx = blockIdx.x * 256 + threadIdx.x;
    for (; idx < total4; idx += gridDim.x * 256) {
        int i = idx * 4;
        int c = i & (DD - 1);
        f4 h = *reinterpret_cast<const f4*>(AGG + i);
        f4 o;
        #pragma unroll
        for (int j = 0; j < 4; j++) o.v[j] = fmaxf(h.v[j] * AB[c + j] + AB[DD + c + j], 0.f);
        if (add_old) {
            f4 x = *reinterpret_cast<const f4*>(Xio + i);
            #pragma unroll
            for (int j = 0; j < 4; j++) o.v[j] += x.v[j];
        }
        *reinterpret_cast<f4*>(Xio + i) = o;
    }
}

extern "C" void kernel_launch(void* const* d_in, const int* in_sizes, int n_in,
                              void* d_out, int out_size, void* d_ws, size_t ws_size,
                              hipStream_t stream)
{
    const float* x_in     = (const float*)d_in[0];
    const int*   erow     = (const int*)d_in[1];
    const int*   ecol     = (const int*)d_in[2];
    const float* evalv    = (const float*)d_in[3];
    const float* gamma    = (const float*)d_in[4];
    const float* beta     = (const float*)d_in[5];
    const float* fc_in_w  = (const float*)d_in[6];
    const float* fc_in_b  = (const float*)d_in[7];
    const float* gc_w     = (const float*)d_in[8];
    // d_in[9] = gc_b: provably no-op under PairNorm (column-mean subtraction cancels it)
    const float* fc_out_w = (const float*)d_in[10];
    const float* fc_out_b = (const float*)d_in[11];
    float* out = (float*)d_out;

    const int n = in_sizes[0] / DD;   // 50000
    const int e = in_sizes[1];        // 800000
    const int NB = 512;               // reduce blocks

    char* w = (char*)d_ws;
    float* X    = (float*)w;  w += (size_t)n * DD * 4;
    float* Hb   = (float*)w;  w += (size_t)n * DD * 4;
    float* AGG  = (float*)w;  w += (size_t)n * DD * 4;
    float* PSUM = (float*)w;  w += (size_t)NB * DD * 4;
    float* PSQ  = (float*)w;  w += (size_t)NB * DD * 4;
    float* AB   = (float*)w;  w += 2 * DD * 4;
    int* deg    = (int*)w;    w += (size_t)(n + 4) * 4;
    int* rowptr = (int*)w;    w += (size_t)(n + 4) * 4;
    int* cursor = (int*)w;    w += (size_t)(n + 4) * 4;
    int* ccol   = (int*)w;    w += (size_t)e * 4;
    float* cval = (float*)w;  w += (size_t)e * 4;

    // ---- CSR build (once; edges constant across layers) ----
    hipMemsetAsync(deg, 0, (size_t)n * 4, stream);
    hist_k<<<(e + 255) / 256, 256, 0, stream>>>(erow, deg, e);
    scan_k<<<1, 1024, 0, stream>>>(deg, rowptr, cursor, n);
    scatter_k<<<(e + 255) / 256, 256, 0, stream>>>(erow, ecol, evalv, cursor, ccol, cval, e);

    // ---- BatchNorm stats + fused BN + fc_in GEMM ----
    col_reduce_k<<<NB, 256, 0, stream>>>(x_in, n, PSUM, PSQ);
    bn_finalize_k<<<1, DD, 0, stream>>>(PSUM, PSQ, NB, n, gamma, beta, AB);
    const int gblocks = (n + 31) / 32;
    gemm_k128<DD, true, true><<<gblocks, 256, 0, stream>>>(x_in, fc_in_w, fc_in_b, AB, X, n);

    // ---- 4 GCN layers ----
    for (int l = 0; l < 4; l++) {
        gemm_k128<DD, false, false><<<gblocks, 256, 0, stream>>>(
            X, gc_w + (size_t)l * DD * DD, nullptr, nullptr, Hb, n);
        spmm_csr_k<<<((size_t)n * 32 + 255) / 256, 256, 0, stream>>>(rowptr, ccol, cval, Hb, AGG, n);
        col_reduce_k<<<NB, 256, 0, stream>>>(AGG, n, PSUM, PSQ);
        pn_finalize_k<<<1, DD, 0, stream>>>(PSUM, PSQ, NB, n, AB);
        pn_apply_k<<<2048, 256, 0, stream>>>(AGG, AB, X, n * DD / 4, l > 0 ? 1 : 0);
    }

    // ---- fc_out ----
    gemm_k128<40, false, true><<<gblocks, 256, 0, stream>>>(X, fc_out_w, fc_out_b, nullptr, out, n);
}

// Round 2
// 1412.147 us; speedup vs baseline: 3.1310x; 3.1310x over previous
//
#include <hip/hip_runtime.h>
#include <hip/hip_bf16.h>

// DeepGCN forward: BN -> fc_in -> 4x[GEMM -> SpMM -> PairNorm -> ReLU -> residual] -> fc_out
// fp32 throughout. CSR built on-device once per launch (edges constant across layers).
// R1: bounded unroll in GEMM k-loop (was full-unroll -> 256 VGPR + 1.6GB/dispatch spill traffic).

constexpr int DD = 128;

struct alignas(16) f4 { float v[4]; };

// ---------------- column reduce: per-block partial colsum/colsumsq ----------------
__global__ __launch_bounds__(256) void col_reduce_k(const float* __restrict__ X, int n,
    float* __restrict__ psum, float* __restrict__ psq)
{
    int c = threadIdx.x & (DD - 1);
    int half = threadIdx.x >> 7;
    int rows_per_blk = (n + gridDim.x - 1) / gridDim.x;
    int r0 = blockIdx.x * rows_per_blk;
    int r1 = min(n, r0 + rows_per_blk);
    float s = 0.f, ss = 0.f;
    for (int r = r0 + half; r < r1; r += 2) {
        float v = X[(size_t)r * DD + c];
        s += v; ss += v * v;
    }
    __shared__ float ls[256], lq[256];
    ls[threadIdx.x] = s; lq[threadIdx.x] = ss;
    __syncthreads();
    if (half == 0) {
        psum[blockIdx.x * DD + c] = ls[c] + ls[c + 128];
        psq [blockIdx.x * DD + c] = lq[c] + lq[c + 128];
    }
}

// ---------------- BN finalize: A = gamma*rstd, B = beta - mu*A ----------------
__global__ void bn_finalize_k(const float* __restrict__ psum, const float* __restrict__ psq,
    int nblk, int n, const float* __restrict__ gamma, const float* __restrict__ beta,
    float* __restrict__ AB)
{
    int c = threadIdx.x;  // 128 threads
    float s = 0.f, ss = 0.f;
    for (int b = 0; b < nblk; b++) { s += psum[b * DD + c]; ss += psq[b * DD + c]; }
    float mu = s / (float)n;
    float var = ss / (float)n - mu * mu;
    float a = gamma[c] * rsqrtf(var + 1e-5f);
    AB[c] = a;
    AB[DD + c] = beta[c] - mu * a;
}

// ---------------- PairNorm finalize: A = inv_rn, B = -mu*inv_rn ----------------
__global__ void pn_finalize_k(const float* __restrict__ psum, const float* __restrict__ psq,
    int nblk, int n, float* __restrict__ AB)
{
    int c = threadIdx.x;  // 128 threads
    float s = 0.f, ss = 0.f;
    for (int b = 0; b < nblk; b++) { s += psum[b * DD + c]; ss += psq[b * DD + c]; }
    float mu = s / (float)n;
    float cent = ss - (float)n * mu * mu;   // per-col centered sumsq
    __shared__ float red[DD];
    red[c] = cent;
    __syncthreads();
    for (int off = 64; off > 0; off >>= 1) {
        if (c < off) red[c] += red[c + off];
        __syncthreads();
    }
    float inv = rsqrtf(1e-6f + red[0] / (float)n);
    AB[c] = inv;
    AB[DD + c] = -mu * inv;
}

// ---------------- GEMM: Y[n,NCOL] = X[n,128] @ W[128,NCOL] (+bias) ----------------
// INSCALE: apply x*A[k]+B[k] per input column while staging (fused BatchNorm).
template<int NCOL, bool INSCALE, bool BIAS>
__global__ __launch_bounds__(256) void gemm_k128(const float* __restrict__ X,
    const float* __restrict__ W, const float* __restrict__ bias,
    const float* __restrict__ AB, float* __restrict__ Y, int n)
{
    __shared__ float xs[32][DD];
    __shared__ float ws[DD][NCOL];
    const int t = threadIdx.x;

    // stage W (full) into LDS
    {
        const f4* Wv = reinterpret_cast<const f4*>(W);
        f4* wsv = reinterpret_cast<f4*>(&ws[0][0]);
        for (int i = t; i < DD * NCOL / 4; i += 256) wsv[i] = Wv[i];
    }
    // stage X tile (32 rows)
    const int row0 = blockIdx.x * 32;
    for (int i = t; i < 32 * DD / 4; i += 256) {
        int r = i >> 5;
        int k = (i & 31) << 2;
        f4 v; v.v[0] = v.v[1] = v.v[2] = v.v[3] = 0.f;
        if (row0 + r < n) v = *reinterpret_cast<const f4*>(X + (size_t)(row0 + r) * DD + k);
        if (INSCALE) {
            #pragma unroll
            for (int j = 0; j < 4; j++) v.v[j] = v.v[j] * AB[k + j] + AB[DD + k + j];
        }
        *reinterpret_cast<f4*>(&xs[r][k]) = v;
    }
    __syncthreads();

    constexpr int TC = (NCOL >= 128) ? 32 : 16;  // col groups of 4
    constexpr int TR = 256 / TC;                 // row groups
    constexpr int RPT = 32 / TR;                 // rows per thread
    const int tc = t % TC, tr = t / TC;
    const int c0 = tc * 4;
    const int r0 = tr * RPT;
    if (c0 < NCOL) {
        float acc[RPT][4];
        #pragma unroll
        for (int i = 0; i < RPT; i++)
            #pragma unroll
            for (int j = 0; j < 4; j++) acc[i][j] = 0.f;

        // Bounded unroll: full unroll here previously hoisted ~256 ds_reads,
        // maxed VGPRs at 256 and spilled 1.6GB/dispatch to scratch.
        #pragma unroll 2
        for (int k0 = 0; k0 < DD; k0 += 4) {
            f4 a[RPT], w[4];
            #pragma unroll
            for (int i = 0; i < RPT; i++) a[i] = *reinterpret_cast<const f4*>(&xs[r0 + i][k0]);
            #pragma unroll
            for (int q = 0; q < 4; q++) w[q] = *reinterpret_cast<const f4*>(&ws[k0 + q][c0]);
            #pragma unroll
            for (int i = 0; i < RPT; i++)
                #pragma unroll
                for (int q = 0; q < 4; q++)
                    #pragma unroll
                    for (int j = 0; j < 4; j++)
                        acc[i][j] = fmaf(a[i].v[q], w[q].v[j], acc[i][j]);
        }

        #pragma unroll
        for (int i = 0; i < RPT; i++) {
            int r = row0 + r0 + i;
            if (r < n) {
                f4 o;
                #pragma unroll
                for (int j = 0; j < 4; j++) o.v[j] = acc[i][j] + (BIAS ? bias[c0 + j] : 0.f);
                *reinterpret_cast<f4*>(Y + (size_t)r * NCOL + c0) = o;
            }
        }
    }
}

// ---------------- CSR build ----------------
__global__ __launch_bounds__(256) void hist_k(const int* __restrict__ erow,
    int* __restrict__ deg, int e)
{
    int i = blockIdx.x * 256 + threadIdx.x;
    if (i < e) atomicAdd(&deg[erow[i]], 1);
}

__global__ __launch_bounds__(1024) void scan_k(const int* __restrict__ deg,
    int* __restrict__ rowptr, int* __restrict__ cursor, int n)
{
    const int T = 1024;
    int t = threadIdx.x;
    int chunk = (n + T - 1) / T;
    int lo = min(n, t * chunk), hi = min(n, lo + chunk);
    int s = 0;
    for (int i = lo; i < hi; i++) s += deg[i];
    __shared__ int ps[T];
    ps[t] = s;
    __syncthreads();
    for (int off = 1; off < T; off <<= 1) {
        int add = (t >= off) ? ps[t - off] : 0;
        __syncthreads();
        ps[t] += add;
        __syncthreads();
    }
    int run = (t > 0) ? ps[t - 1] : 0;
    for (int i = lo; i < hi; i++) {
        int d = deg[i];
        rowptr[i] = run;
        cursor[i] = run;
        run += d;
    }
    if (t == T - 1) rowptr[n] = ps[T - 1];
}

__global__ __launch_bounds__(256) void scatter_k(const int* __restrict__ erow,
    const int* __restrict__ ecol, const float* __restrict__ evalv,
    int* __restrict__ cursor, int* __restrict__ ccol, float* __restrict__ cval, int e)
{
    int i = blockIdx.x * 256 + threadIdx.x;
    if (i >= e) return;
    int r = erow[i];
    int p = atomicAdd(&cursor[r], 1);
    ccol[p] = ecol[i];
    cval[p] = evalv[i];
}

// ---------------- SpMM (CSR gather): AGG[r,:] = sum_e val*H[col,:] ----------------
__global__ __launch_bounds__(256) void spmm_csr_k(const int* __restrict__ rowptr,
    const int* __restrict__ ccol, const float* __restrict__ cval,
    const float* __restrict__ H, float* __restrict__ AGG, int n)
{
    int g = blockIdx.x * 256 + threadIdx.x;
    int r = g >> 5;          // 32 threads per row
    int lane = g & 31;       // 4 floats each
    if (r >= n) return;
    int p0 = rowptr[r], p1 = rowptr[r + 1];
    float ax = 0.f, ay = 0.f, az = 0.f, aw = 0.f;
    for (int p = p0; p < p1; p++) {
        int c = ccol[p];
        float v = cval[p];
        const f4 h = *reinterpret_cast<const f4*>(H + (size_t)c * DD + lane * 4);
        ax = fmaf(v, h.v[0], ax);
        ay = fmaf(v, h.v[1], ay);
        az = fmaf(v, h.v[2], az);
        aw = fmaf(v, h.v[3], aw);
    }
    f4 o; o.v[0] = ax; o.v[1] = ay; o.v[2] = az; o.v[3] = aw;
    *reinterpret_cast<f4*>(AGG + (size_t)r * DD + lane * 4) = o;
}

// ---------------- PairNorm apply + ReLU + residual (in place on X) ----------------
__global__ __launch_bounds__(256) void pn_apply_k(const float* __restrict__ AGG,
    const float* __restrict__ AB, float* __restrict__ Xio, int total4, int add_old)
{
    int idx = blockIdx.x * 256 + threadIdx.x;
    for (; idx < total4; idx += gridDim.x * 256) {
        int i = idx * 4;
        int c = i & (DD - 1);
        f4 h = *reinterpret_cast<const f4*>(AGG + i);
        f4 o;
        #pragma unroll
        for (int j = 0; j < 4; j++) o.v[j] = fmaxf(h.v[j] * AB[c + j] + AB[DD + c + j], 0.f);
        if (add_old) {
            f4 x = *reinterpret_cast<const f4*>(Xio + i);
            #pragma unroll
            for (int j = 0; j < 4; j++) o.v[j] += x.v[j];
        }
        *reinterpret_cast<f4*>(Xio + i) = o;
    }
}

extern "C" void kernel_launch(void* const* d_in, const int* in_sizes, int n_in,
                              void* d_out, int out_size, void* d_ws, size_t ws_size,
                              hipStream_t stream)
{
    const float* x_in     = (const float*)d_in[0];
    const int*   erow     = (const int*)d_in[1];
    const int*   ecol     = (const int*)d_in[2];
    const float* evalv    = (const float*)d_in[3];
    const float* gamma    = (const float*)d_in[4];
    const float* beta     = (const float*)d_in[5];
    const float* fc_in_w  = (const float*)d_in[6];
    const float* fc_in_b  = (const float*)d_in[7];
    const float* gc_w     = (const float*)d_in[8];
    // d_in[9] = gc_b: provably no-op under PairNorm (column-mean subtraction cancels it)
    const float* fc_out_w = (const float*)d_in[10];
    const float* fc_out_b = (const float*)d_in[11];
    float* out = (float*)d_out;

    const int n = in_sizes[0] / DD;   // 50000
    const int e = in_sizes[1];        // 800000
    const int NB = 512;               // reduce blocks

    char* w = (char*)d_ws;
    float* X    = (float*)w;  w += (size_t)n * DD * 4;
    float* Hb   = (float*)w;  w += (size_t)n * DD * 4;
    float* AGG  = (float*)w;  w += (size_t)n * DD * 4;
    float* PSUM = (float*)w;  w += (size_t)NB * DD * 4;
    float* PSQ  = (float*)w;  w += (size_t)NB * DD * 4;
    float* AB   = (float*)w;  w += 2 * DD * 4;
    int* deg    = (int*)w;    w += (size_t)(n + 4) * 4;
    int* rowptr = (int*)w;    w += (size_t)(n + 4) * 4;
    int* cursor = (int*)w;    w += (size_t)(n + 4) * 4;
    int* ccol   = (int*)w;    w += (size_t)e * 4;
    float* cval = (float*)w;  w += (size_t)e * 4;

    // ---- CSR build (once; edges constant across layers) ----
    hipMemsetAsync(deg, 0, (size_t)n * 4, stream);
    hist_k<<<(e + 255) / 256, 256, 0, stream>>>(erow, deg, e);
    scan_k<<<1, 1024, 0, stream>>>(deg, rowptr, cursor, n);
    scatter_k<<<(e + 255) / 256, 256, 0, stream>>>(erow, ecol, evalv, cursor, ccol, cval, e);

    // ---- BatchNorm stats + fused BN + fc_in GEMM ----
    col_reduce_k<<<NB, 256, 0, stream>>>(x_in, n, PSUM, PSQ);
    bn_finalize_k<<<1, DD, 0, stream>>>(PSUM, PSQ, NB, n, gamma, beta, AB);
    const int gblocks = (n + 31) / 32;
    gemm_k128<DD, true, true><<<gblocks, 256, 0, stream>>>(x_in, fc_in_w, fc_in_b, AB, X, n);

    // ---- 4 GCN layers ----
    for (int l = 0; l < 4; l++) {
        gemm_k128<DD, false, false><<<gblocks, 256, 0, stream>>>(
            X, gc_w + (size_t)l * DD * DD, nullptr, nullptr, Hb, n);
        spmm_csr_k<<<((size_t)n * 32 + 255) / 256, 256, 0, stream>>>(rowptr, ccol, cval, Hb, AGG, n);
        col_reduce_k<<<NB, 256, 0, stream>>>(AGG, n, PSUM, PSQ);
        pn_finalize_k<<<1, DD, 0, stream>>>(PSUM, PSQ, NB, n, AB);
        pn_apply_k<<<2048, 256, 0, stream>>>(AGG, AB, X, n * DD / 4, l > 0 ? 1 : 0);
    }

    // ---- fc_out ----
    gemm_k128<40, false, true><<<gblocks, 256, 0, stream>>>(X, fc_out_w, fc_out_b, nullptr, out, n);
}

// Round 3
// 886.248 us; speedup vs baseline: 4.9889x; 1.5934x over previous
//
#include <hip/hip_runtime.h>
#include <hip/hip_bf16.h>

// DeepGCN forward: BN -> fc_in -> 4x[GEMM -> SpMM -> PairNorm -> ReLU -> residual] -> fc_out
// fp32 throughout. CSR built on-device once per launch (edges constant across layers).
// R1: bounded unroll in GEMM k-loop (was full-unroll -> 256 VGPR + 1.6GB/dispatch spill traffic).
// R2: finalize kernels were 1-block/128-thread latency chains over 512 partials
//     (~129us each, 5 dispatches = 46% of runtime). Now 1024 threads, 8-way strided
//     partial sums + LDS combine -> predicted ~5-8us each.

constexpr int DD = 128;

struct alignas(16) f4 { float v[4]; };

// ---------------- column reduce: per-block partial colsum/colsumsq ----------------
__global__ __launch_bounds__(256) void col_reduce_k(const float* __restrict__ X, int n,
    float* __restrict__ psum, float* __restrict__ psq)
{
    int c = threadIdx.x & (DD - 1);
    int half = threadIdx.x >> 7;
    int rows_per_blk = (n + gridDim.x - 1) / gridDim.x;
    int r0 = blockIdx.x * rows_per_blk;
    int r1 = min(n, r0 + rows_per_blk);
    float s = 0.f, ss = 0.f;
    for (int r = r0 + half; r < r1; r += 2) {
        float v = X[(size_t)r * DD + c];
        s += v; ss += v * v;
    }
    __shared__ float ls[256], lq[256];
    ls[threadIdx.x] = s; lq[threadIdx.x] = ss;
    __syncthreads();
    if (half == 0) {
        psum[blockIdx.x * DD + c] = ls[c] + ls[c + 128];
        psq [blockIdx.x * DD + c] = lq[c] + lq[c + 128];
    }
}

// ---------------- finalize (BN or PN): parallel over 8 partial-groups ----------------
// BN: A = gamma*rstd, B = beta - mu*A.   PN: A = inv_rn, B = -mu*inv_rn.
template<bool BN>
__global__ __launch_bounds__(1024) void finalize_k(const float* __restrict__ psum,
    const float* __restrict__ psq, int nblk, int n,
    const float* __restrict__ gamma, const float* __restrict__ beta,
    float* __restrict__ AB)
{
    const int c = threadIdx.x & (DD - 1);
    const int g = threadIdx.x >> 7;   // 0..7
    float s = 0.f, ss = 0.f;
    for (int b = g; b < nblk; b += 8) {
        s  += psum[b * DD + c];
        ss += psq [b * DD + c];
    }
    __shared__ float Ls[8][DD], Lq[8][DD];
    Ls[g][c] = s; Lq[g][c] = ss;
    __syncthreads();
    // every group redundantly computes the full column sums (uniform control flow)
    float ts = 0.f, tss = 0.f;
    #pragma unroll
    for (int k = 0; k < 8; k++) { ts += Ls[k][c]; tss += Lq[k][c]; }
    float mu = ts / (float)n;
    if (BN) {
        if (threadIdx.x < DD) {
            float var = tss / (float)n - mu * mu;
            float a = gamma[c] * rsqrtf(var + 1e-5f);
            AB[c] = a;
            AB[DD + c] = beta[c] - mu * a;
        }
    } else {
        float cent = tss - (float)n * mu * mu;   // per-col centered sumsq (same in all groups)
        __syncthreads();
        if (g == 0) Ls[0][c] = cent;
        __syncthreads();
        for (int off = 64; off > 0; off >>= 1) {
            if (threadIdx.x < off) Ls[0][threadIdx.x] += Ls[0][threadIdx.x + off];
            __syncthreads();
        }
        if (threadIdx.x < DD) {
            float inv = rsqrtf(1e-6f + Ls[0][0] / (float)n);
            AB[c] = inv;
            AB[DD + c] = -mu * inv;
        }
    }
}

// ---------------- GEMM: Y[n,NCOL] = X[n,128] @ W[128,NCOL] (+bias) ----------------
// INSCALE: apply x*A[k]+B[k] per input column while staging (fused BatchNorm).
template<int NCOL, bool INSCALE, bool BIAS>
__global__ __launch_bounds__(256) void gemm_k128(const float* __restrict__ X,
    const float* __restrict__ W, const float* __restrict__ bias,
    const float* __restrict__ AB, float* __restrict__ Y, int n)
{
    __shared__ float xs[32][DD];
    __shared__ float ws[DD][NCOL];
    const int t = threadIdx.x;

    // stage W (full) into LDS
    {
        const f4* Wv = reinterpret_cast<const f4*>(W);
        f4* wsv = reinterpret_cast<f4*>(&ws[0][0]);
        for (int i = t; i < DD * NCOL / 4; i += 256) wsv[i] = Wv[i];
    }
    // stage X tile (32 rows)
    const int row0 = blockIdx.x * 32;
    for (int i = t; i < 32 * DD / 4; i += 256) {
        int r = i >> 5;
        int k = (i & 31) << 2;
        f4 v; v.v[0] = v.v[1] = v.v[2] = v.v[3] = 0.f;
        if (row0 + r < n) v = *reinterpret_cast<const f4*>(X + (size_t)(row0 + r) * DD + k);
        if (INSCALE) {
            #pragma unroll
            for (int j = 0; j < 4; j++) v.v[j] = v.v[j] * AB[k + j] + AB[DD + k + j];
        }
        *reinterpret_cast<f4*>(&xs[r][k]) = v;
    }
    __syncthreads();

    constexpr int TC = (NCOL >= 128) ? 32 : 16;  // col groups of 4
    constexpr int TR = 256 / TC;                 // row groups
    constexpr int RPT = 32 / TR;                 // rows per thread
    const int tc = t % TC, tr = t / TC;
    const int c0 = tc * 4;
    const int r0 = tr * RPT;
    if (c0 < NCOL) {
        float acc[RPT][4];
        #pragma unroll
        for (int i = 0; i < RPT; i++)
            #pragma unroll
            for (int j = 0; j < 4; j++) acc[i][j] = 0.f;

        // Bounded unroll: full unroll here previously hoisted ~256 ds_reads,
        // maxed VGPRs at 256 and spilled 1.6GB/dispatch to scratch.
        #pragma unroll 2
        for (int k0 = 0; k0 < DD; k0 += 4) {
            f4 a[RPT], w[4];
            #pragma unroll
            for (int i = 0; i < RPT; i++) a[i] = *reinterpret_cast<const f4*>(&xs[r0 + i][k0]);
            #pragma unroll
            for (int q = 0; q < 4; q++) w[q] = *reinterpret_cast<const f4*>(&ws[k0 + q][c0]);
            #pragma unroll
            for (int i = 0; i < RPT; i++)
                #pragma unroll
                for (int q = 0; q < 4; q++)
                    #pragma unroll
                    for (int j = 0; j < 4; j++)
                        acc[i][j] = fmaf(a[i].v[q], w[q].v[j], acc[i][j]);
        }

        #pragma unroll
        for (int i = 0; i < RPT; i++) {
            int r = row0 + r0 + i;
            if (r < n) {
                f4 o;
                #pragma unroll
                for (int j = 0; j < 4; j++) o.v[j] = acc[i][j] + (BIAS ? bias[c0 + j] : 0.f);
                *reinterpret_cast<f4*>(Y + (size_t)r * NCOL + c0) = o;
            }
        }
    }
}

// ---------------- CSR build ----------------
__global__ __launch_bounds__(256) void hist_k(const int* __restrict__ erow,
    int* __restrict__ deg, int e)
{
    int i = blockIdx.x * 256 + threadIdx.x;
    if (i < e) atomicAdd(&deg[erow[i]], 1);
}

__global__ __launch_bounds__(1024) void scan_k(const int* __restrict__ deg,
    int* __restrict__ rowptr, int* __restrict__ cursor, int n)
{
    const int T = 1024;
    int t = threadIdx.x;
    int chunk = (n + T - 1) / T;
    int lo = min(n, t * chunk), hi = min(n, lo + chunk);
    int s = 0;
    for (int i = lo; i < hi; i++) s += deg[i];
    __shared__ int ps[T];
    ps[t] = s;
    __syncthreads();
    for (int off = 1; off < T; off <<= 1) {
        int add = (t >= off) ? ps[t - off] : 0;
        __syncthreads();
        ps[t] += add;
        __syncthreads();
    }
    int run = (t > 0) ? ps[t - 1] : 0;
    for (int i = lo; i < hi; i++) {
        int d = deg[i];
        rowptr[i] = run;
        cursor[i] = run;
        run += d;
    }
    if (t == T - 1) rowptr[n] = ps[T - 1];
}

__global__ __launch_bounds__(256) void scatter_k(const int* __restrict__ erow,
    const int* __restrict__ ecol, const float* __restrict__ evalv,
    int* __restrict__ cursor, int* __restrict__ ccol, float* __restrict__ cval, int e)
{
    int i = blockIdx.x * 256 + threadIdx.x;
    if (i >= e) return;
    int r = erow[i];
    int p = atomicAdd(&cursor[r], 1);
    ccol[p] = ecol[i];
    cval[p] = evalv[i];
}

// ---------------- SpMM (CSR gather): AGG[r,:] = sum_e val*H[col,:] ----------------
__global__ __launch_bounds__(256) void spmm_csr_k(const int* __restrict__ rowptr,
    const int* __restrict__ ccol, const float* __restrict__ cval,
    const float* __restrict__ H, float* __restrict__ AGG, int n)
{
    int g = blockIdx.x * 256 + threadIdx.x;
    int r = g >> 5;          // 32 threads per row
    int lane = g & 31;       // 4 floats each
    if (r >= n) return;
    int p0 = rowptr[r], p1 = rowptr[r + 1];
    float ax = 0.f, ay = 0.f, az = 0.f, aw = 0.f;
    for (int p = p0; p < p1; p++) {
        int c = ccol[p];
        float v = cval[p];
        const f4 h = *reinterpret_cast<const f4*>(H + (size_t)c * DD + lane * 4);
        ax = fmaf(v, h.v[0], ax);
        ay = fmaf(v, h.v[1], ay);
        az = fmaf(v, h.v[2], az);
        aw = fmaf(v, h.v[3], aw);
    }
    f4 o; o.v[0] = ax; o.v[1] = ay; o.v[2] = az; o.v[3] = aw;
    *reinterpret_cast<f4*>(AGG + (size_t)r * DD + lane * 4) = o;
}

// ---------------- PairNorm apply + ReLU + residual (in place on X) ----------------
__global__ __launch_bounds__(256) void pn_apply_k(const float* __restrict__ AGG,
    const float* __restrict__ AB, float* __restrict__ Xio, int total4, int add_old)
{
    int idx = blockIdx.x * 256 + threadIdx.x;
    for (; idx < total4; idx += gridDim.x * 256) {
        int i = idx * 4;
        int c = i & (DD - 1);
        f4 h = *reinterpret_cast<const f4*>(AGG + i);
        f4 o;
        #pragma unroll
        for (int j = 0; j < 4; j++) o.v[j] = fmaxf(h.v[j] * AB[c + j] + AB[DD + c + j], 0.f);
        if (add_old) {
            f4 x = *reinterpret_cast<const f4*>(Xio + i);
            #pragma unroll
            for (int j = 0; j < 4; j++) o.v[j] += x.v[j];
        }
        *reinterpret_cast<f4*>(Xio + i) = o;
    }
}

extern "C" void kernel_launch(void* const* d_in, const int* in_sizes, int n_in,
                              void* d_out, int out_size, void* d_ws, size_t ws_size,
                              hipStream_t stream)
{
    const float* x_in     = (const float*)d_in[0];
    const int*   erow     = (const int*)d_in[1];
    const int*   ecol     = (const int*)d_in[2];
    const float* evalv    = (const float*)d_in[3];
    const float* gamma    = (const float*)d_in[4];
    const float* beta     = (const float*)d_in[5];
    const float* fc_in_w  = (const float*)d_in[6];
    const float* fc_in_b  = (const float*)d_in[7];
    const float* gc_w     = (const float*)d_in[8];
    // d_in[9] = gc_b: provably no-op under PairNorm (column-mean subtraction cancels it)
    const float* fc_out_w = (const float*)d_in[10];
    const float* fc_out_b = (const float*)d_in[11];
    float* out = (float*)d_out;

    const int n = in_sizes[0] / DD;   // 50000
    const int e = in_sizes[1];        // 800000
    const int NB = 512;               // reduce blocks

    char* w = (char*)d_ws;
    float* X    = (float*)w;  w += (size_t)n * DD * 4;
    float* Hb   = (float*)w;  w += (size_t)n * DD * 4;
    float* AGG  = (float*)w;  w += (size_t)n * DD * 4;
    float* PSUM = (float*)w;  w += (size_t)NB * DD * 4;
    float* PSQ  = (float*)w;  w += (size_t)NB * DD * 4;
    float* AB   = (float*)w;  w += 2 * DD * 4;
    int* deg    = (int*)w;    w += (size_t)(n + 4) * 4;
    int* rowptr = (int*)w;    w += (size_t)(n + 4) * 4;
    int* cursor = (int*)w;    w += (size_t)(n + 4) * 4;
    int* ccol   = (int*)w;    w += (size_t)e * 4;
    float* cval = (float*)w;  w += (size_t)e * 4;

    // ---- CSR build (once; edges constant across layers) ----
    hipMemsetAsync(deg, 0, (size_t)n * 4, stream);
    hist_k<<<(e + 255) / 256, 256, 0, stream>>>(erow, deg, e);
    scan_k<<<1, 1024, 0, stream>>>(deg, rowptr, cursor, n);
    scatter_k<<<(e + 255) / 256, 256, 0, stream>>>(erow, ecol, evalv, cursor, ccol, cval, e);

    // ---- BatchNorm stats + fused BN + fc_in GEMM ----
    col_reduce_k<<<NB, 256, 0, stream>>>(x_in, n, PSUM, PSQ);
    finalize_k<true><<<1, 1024, 0, stream>>>(PSUM, PSQ, NB, n, gamma, beta, AB);
    const int gblocks = (n + 31) / 32;
    gemm_k128<DD, true, true><<<gblocks, 256, 0, stream>>>(x_in, fc_in_w, fc_in_b, AB, X, n);

    // ---- 4 GCN layers ----
    for (int l = 0; l < 4; l++) {
        gemm_k128<DD, false, false><<<gblocks, 256, 0, stream>>>(
            X, gc_w + (size_t)l * DD * DD, nullptr, nullptr, Hb, n);
        spmm_csr_k<<<((size_t)n * 32 + 255) / 256, 256, 0, stream>>>(rowptr, ccol, cval, Hb, AGG, n);
        col_reduce_k<<<NB, 256, 0, stream>>>(AGG, n, PSUM, PSQ);
        finalize_k<false><<<1, 1024, 0, stream>>>(PSUM, PSQ, NB, n, nullptr, nullptr, AB);
        pn_apply_k<<<2048, 256, 0, stream>>>(AGG, AB, X, n * DD / 4, l > 0 ? 1 : 0);
    }

    // ---- fc_out ----
    gemm_k128<40, false, true><<<gblocks, 256, 0, stream>>>(X, fc_out_w, fc_out_b, nullptr, out, n);
}

// Round 4
// 786.449 us; speedup vs baseline: 5.6220x; 1.1269x over previous
//
#include <hip/hip_runtime.h>
#include <hip/hip_bf16.h>

// DeepGCN forward: BN -> fc_in -> 4x[GEMM -> SpMM -> PairNorm -> ReLU -> residual] -> fc_out
// fp32 throughout. CSR built on-device once per launch (edges constant across layers).
// R1: bounded unroll in GEMM k-loop (was full-unroll -> 256 VGPR + 1.6GB/dispatch spill traffic).
// R2: finalize kernels 1-block latency chains -> 1024-thread 8-way strided (129us -> ~5us).
// R3: scan_k was a 1-block serial scan (111us, worst dispatch). Now 3-phase multi-block
//     scan with int4-coalesced I/O -> predicted ~6-10us total.

constexpr int DD = 128;

struct alignas(16) f4 { float v[4]; };

// ---------------- column reduce: per-block partial colsum/colsumsq ----------------
__global__ __launch_bounds__(256) void col_reduce_k(const float* __restrict__ X, int n,
    float* __restrict__ psum, float* __restrict__ psq)
{
    int c = threadIdx.x & (DD - 1);
    int half = threadIdx.x >> 7;
    int rows_per_blk = (n + gridDim.x - 1) / gridDim.x;
    int r0 = blockIdx.x * rows_per_blk;
    int r1 = min(n, r0 + rows_per_blk);
    float s = 0.f, ss = 0.f;
    for (int r = r0 + half; r < r1; r += 2) {
        float v = X[(size_t)r * DD + c];
        s += v; ss += v * v;
    }
    __shared__ float ls[256], lq[256];
    ls[threadIdx.x] = s; lq[threadIdx.x] = ss;
    __syncthreads();
    if (half == 0) {
        psum[blockIdx.x * DD + c] = ls[c] + ls[c + 128];
        psq [blockIdx.x * DD + c] = lq[c] + lq[c + 128];
    }
}

// ---------------- finalize (BN or PN): parallel over 8 partial-groups ----------------
// BN: A = gamma*rstd, B = beta - mu*A.   PN: A = inv_rn, B = -mu*inv_rn.
template<bool BN>
__global__ __launch_bounds__(1024) void finalize_k(const float* __restrict__ psum,
    const float* __restrict__ psq, int nblk, int n,
    const float* __restrict__ gamma, const float* __restrict__ beta,
    float* __restrict__ AB)
{
    const int c = threadIdx.x & (DD - 1);
    const int g = threadIdx.x >> 7;   // 0..7
    float s = 0.f, ss = 0.f;
    for (int b = g; b < nblk; b += 8) {
        s  += psum[b * DD + c];
        ss += psq [b * DD + c];
    }
    __shared__ float Ls[8][DD], Lq[8][DD];
    Ls[g][c] = s; Lq[g][c] = ss;
    __syncthreads();
    // every group redundantly computes the full column sums (uniform control flow)
    float ts = 0.f, tss = 0.f;
    #pragma unroll
    for (int k = 0; k < 8; k++) { ts += Ls[k][c]; tss += Lq[k][c]; }
    float mu = ts / (float)n;
    if (BN) {
        if (threadIdx.x < DD) {
            float var = tss / (float)n - mu * mu;
            float a = gamma[c] * rsqrtf(var + 1e-5f);
            AB[c] = a;
            AB[DD + c] = beta[c] - mu * a;
        }
    } else {
        float cent = tss - (float)n * mu * mu;   // per-col centered sumsq (same in all groups)
        __syncthreads();
        if (g == 0) Ls[0][c] = cent;
        __syncthreads();
        for (int off = 64; off > 0; off >>= 1) {
            if (threadIdx.x < off) Ls[0][threadIdx.x] += Ls[0][threadIdx.x + off];
            __syncthreads();
        }
        if (threadIdx.x < DD) {
            float inv = rsqrtf(1e-6f + Ls[0][0] / (float)n);
            AB[c] = inv;
            AB[DD + c] = -mu * inv;
        }
    }
}

// ---------------- GEMM: Y[n,NCOL] = X[n,128] @ W[128,NCOL] (+bias) ----------------
// INSCALE: apply x*A[k]+B[k] per input column while staging (fused BatchNorm).
template<int NCOL, bool INSCALE, bool BIAS>
__global__ __launch_bounds__(256) void gemm_k128(const float* __restrict__ X,
    const float* __restrict__ W, const float* __restrict__ bias,
    const float* __restrict__ AB, float* __restrict__ Y, int n)
{
    __shared__ float xs[32][DD];
    __shared__ float ws[DD][NCOL];
    const int t = threadIdx.x;

    // stage W (full) into LDS
    {
        const f4* Wv = reinterpret_cast<const f4*>(W);
        f4* wsv = reinterpret_cast<f4*>(&ws[0][0]);
        for (int i = t; i < DD * NCOL / 4; i += 256) wsv[i] = Wv[i];
    }
    // stage X tile (32 rows)
    const int row0 = blockIdx.x * 32;
    for (int i = t; i < 32 * DD / 4; i += 256) {
        int r = i >> 5;
        int k = (i & 31) << 2;
        f4 v; v.v[0] = v.v[1] = v.v[2] = v.v[3] = 0.f;
        if (row0 + r < n) v = *reinterpret_cast<const f4*>(X + (size_t)(row0 + r) * DD + k);
        if (INSCALE) {
            #pragma unroll
            for (int j = 0; j < 4; j++) v.v[j] = v.v[j] * AB[k + j] + AB[DD + k + j];
        }
        *reinterpret_cast<f4*>(&xs[r][k]) = v;
    }
    __syncthreads();

    constexpr int TC = (NCOL >= 128) ? 32 : 16;  // col groups of 4
    constexpr int TR = 256 / TC;                 // row groups
    constexpr int RPT = 32 / TR;                 // rows per thread
    const int tc = t % TC, tr = t / TC;
    const int c0 = tc * 4;
    const int r0 = tr * RPT;
    if (c0 < NCOL) {
        float acc[RPT][4];
        #pragma unroll
        for (int i = 0; i < RPT; i++)
            #pragma unroll
            for (int j = 0; j < 4; j++) acc[i][j] = 0.f;

        // Bounded unroll: full unroll here previously hoisted ~256 ds_reads,
        // maxed VGPRs at 256 and spilled 1.6GB/dispatch to scratch.
        #pragma unroll 2
        for (int k0 = 0; k0 < DD; k0 += 4) {
            f4 a[RPT], w[4];
            #pragma unroll
            for (int i = 0; i < RPT; i++) a[i] = *reinterpret_cast<const f4*>(&xs[r0 + i][k0]);
            #pragma unroll
            for (int q = 0; q < 4; q++) w[q] = *reinterpret_cast<const f4*>(&ws[k0 + q][c0]);
            #pragma unroll
            for (int i = 0; i < RPT; i++)
                #pragma unroll
                for (int q = 0; q < 4; q++)
                    #pragma unroll
                    for (int j = 0; j < 4; j++)
                        acc[i][j] = fmaf(a[i].v[q], w[q].v[j], acc[i][j]);
        }

        #pragma unroll
        for (int i = 0; i < RPT; i++) {
            int r = row0 + r0 + i;
            if (r < n) {
                f4 o;
                #pragma unroll
                for (int j = 0; j < 4; j++) o.v[j] = acc[i][j] + (BIAS ? bias[c0 + j] : 0.f);
                *reinterpret_cast<f4*>(Y + (size_t)r * NCOL + c0) = o;
            }
        }
    }
}

// ---------------- CSR build ----------------
__global__ __launch_bounds__(256) void hist_k(const int* __restrict__ erow,
    int* __restrict__ deg, int e)
{
    int i = blockIdx.x * 256 + threadIdx.x;
    if (i < e) atomicAdd(&deg[erow[i]], 1);
}

// 3-phase multi-block exclusive scan over deg[0..n) -> rowptr/cursor, rowptr[n]=total
constexpr int SCAN_TILE = 1024;   // 256 threads x 4 elems

__global__ __launch_bounds__(256) void scan1_k(const int* __restrict__ deg,
    int* __restrict__ local, int* __restrict__ bsum, int n)
{
    const int t = threadIdx.x;
    const int base = blockIdx.x * SCAN_TILE + t * 4;
    int v0 = 0, v1 = 0, v2 = 0, v3 = 0;
    if (base + 3 < n) {
        int4 v = *reinterpret_cast<const int4*>(deg + base);
        v0 = v.x; v1 = v.y; v2 = v.z; v3 = v.w;
    } else {
        if (base + 0 < n) v0 = deg[base + 0];
        if (base + 1 < n) v1 = deg[base + 1];
        if (base + 2 < n) v2 = deg[base + 2];
        if (base + 3 < n) v3 = deg[base + 3];
    }
    int s = v0 + v1 + v2 + v3;
    __shared__ int ps[256];
    ps[t] = s;
    __syncthreads();
    for (int off = 1; off < 256; off <<= 1) {
        int add = (t >= off) ? ps[t - off] : 0;
        __syncthreads();
        ps[t] += add;
        __syncthreads();
    }
    int excl = (t > 0) ? ps[t - 1] : 0;
    int o0 = excl, o1 = excl + v0, o2 = o1 + v1, o3 = o2 + v2;
    if (base + 3 < n) {
        int4 o; o.x = o0; o.y = o1; o.z = o2; o.w = o3;
        *reinterpret_cast<int4*>(local + base) = o;
    } else {
        if (base + 0 < n) local[base + 0] = o0;
        if (base + 1 < n) local[base + 1] = o1;
        if (base + 2 < n) local[base + 2] = o2;
        if (base + 3 < n) local[base + 3] = o3;
    }
    if (t == 255) bsum[blockIdx.x] = ps[255];
}

__global__ __launch_bounds__(256) void scan2_k(const int* __restrict__ bsum,
    int* __restrict__ bpre, int nb, int* __restrict__ rowptr, int n)
{
    const int t = threadIdx.x;
    __shared__ int ps[256];
    ps[t] = (t < nb) ? bsum[t] : 0;
    __syncthreads();
    for (int off = 1; off < 256; off <<= 1) {
        int add = (t >= off) ? ps[t - off] : 0;
        __syncthreads();
        ps[t] += add;
        __syncthreads();
    }
    if (t < nb) bpre[t] = (t > 0) ? ps[t - 1] : 0;
    if (t == 255) rowptr[n] = ps[255];
}

__global__ __launch_bounds__(256) void scan3_k(const int* __restrict__ local,
    const int* __restrict__ bpre, int* __restrict__ rowptr, int* __restrict__ cursor, int n)
{
    const int base = blockIdx.x * SCAN_TILE + threadIdx.x * 4;
    const int p = bpre[blockIdx.x];
    if (base + 3 < n) {
        int4 v = *reinterpret_cast<const int4*>(local + base);
        v.x += p; v.y += p; v.z += p; v.w += p;
        *reinterpret_cast<int4*>(rowptr + base) = v;
        *reinterpret_cast<int4*>(cursor + base) = v;
    } else {
        #pragma unroll
        for (int j = 0; j < 4; j++)
            if (base + j < n) {
                int v = local[base + j] + p;
                rowptr[base + j] = v;
                cursor[base + j] = v;
            }
    }
}

__global__ __launch_bounds__(256) void scatter_k(const int* __restrict__ erow,
    const int* __restrict__ ecol, const float* __restrict__ evalv,
    int* __restrict__ cursor, int* __restrict__ ccol, float* __restrict__ cval, int e)
{
    int i = blockIdx.x * 256 + threadIdx.x;
    if (i >= e) return;
    int r = erow[i];
    int p = atomicAdd(&cursor[r], 1);
    ccol[p] = ecol[i];
    cval[p] = evalv[i];
}

// ---------------- SpMM (CSR gather): AGG[r,:] = sum_e val*H[col,:] ----------------
__global__ __launch_bounds__(256) void spmm_csr_k(const int* __restrict__ rowptr,
    const int* __restrict__ ccol, const float* __restrict__ cval,
    const float* __restrict__ H, float* __restrict__ AGG, int n)
{
    int g = blockIdx.x * 256 + threadIdx.x;
    int r = g >> 5;          // 32 threads per row
    int lane = g & 31;       // 4 floats each
    if (r >= n) return;
    int p0 = rowptr[r], p1 = rowptr[r + 1];
    float ax = 0.f, ay = 0.f, az = 0.f, aw = 0.f;
    for (int p = p0; p < p1; p++) {
        int c = ccol[p];
        float v = cval[p];
        const f4 h = *reinterpret_cast<const f4*>(H + (size_t)c * DD + lane * 4);
        ax = fmaf(v, h.v[0], ax);
        ay = fmaf(v, h.v[1], ay);
        az = fmaf(v, h.v[2], az);
        aw = fmaf(v, h.v[3], aw);
    }
    f4 o; o.v[0] = ax; o.v[1] = ay; o.v[2] = az; o.v[3] = aw;
    *reinterpret_cast<f4*>(AGG + (size_t)r * DD + lane * 4) = o;
}

// ---------------- PairNorm apply + ReLU + residual (in place on X) ----------------
__global__ __launch_bounds__(256) void pn_apply_k(const float* __restrict__ AGG,
    const float* __restrict__ AB, float* __restrict__ Xio, int total4, int add_old)
{
    int idx = blockIdx.x * 256 + threadIdx.x;
    for (; idx < total4; idx += gridDim.x * 256) {
        int i = idx * 4;
        int c = i & (DD - 1);
        f4 h = *reinterpret_cast<const f4*>(AGG + i);
        f4 o;
        #pragma unroll
        for (int j = 0; j < 4; j++) o.v[j] = fmaxf(h.v[j] * AB[c + j] + AB[DD + c + j], 0.f);
        if (add_old) {
            f4 x = *reinterpret_cast<const f4*>(Xio + i);
            #pragma unroll
            for (int j = 0; j < 4; j++) o.v[j] += x.v[j];
        }
        *reinterpret_cast<f4*>(Xio + i) = o;
    }
}

extern "C" void kernel_launch(void* const* d_in, const int* in_sizes, int n_in,
                              void* d_out, int out_size, void* d_ws, size_t ws_size,
                              hipStream_t stream)
{
    const float* x_in     = (const float*)d_in[0];
    const int*   erow     = (const int*)d_in[1];
    const int*   ecol     = (const int*)d_in[2];
    const float* evalv    = (const float*)d_in[3];
    const float* gamma    = (const float*)d_in[4];
    const float* beta     = (const float*)d_in[5];
    const float* fc_in_w  = (const float*)d_in[6];
    const float* fc_in_b  = (const float*)d_in[7];
    const float* gc_w     = (const float*)d_in[8];
    // d_in[9] = gc_b: provably no-op under PairNorm (column-mean subtraction cancels it)
    const float* fc_out_w = (const float*)d_in[10];
    const float* fc_out_b = (const float*)d_in[11];
    float* out = (float*)d_out;

    const int n = in_sizes[0] / DD;   // 50000
    const int e = in_sizes[1];        // 800000
    const int NB = 512;               // reduce blocks
    const int nscan = (n + SCAN_TILE - 1) / SCAN_TILE;   // 49

    char* w = (char*)d_ws;
    float* X    = (float*)w;  w += (size_t)n * DD * 4;
    float* Hb   = (float*)w;  w += (size_t)n * DD * 4;
    float* AGG  = (float*)w;  w += (size_t)n * DD * 4;
    float* PSUM = (float*)w;  w += (size_t)NB * DD * 4;
    float* PSQ  = (float*)w;  w += (size_t)NB * DD * 4;
    float* AB   = (float*)w;  w += 2 * DD * 4;
    int* deg    = (int*)w;    w += (size_t)(n + 4) * 4;
    int* rowptr = (int*)w;    w += (size_t)(n + 4) * 4;
    int* cursor = (int*)w;    w += (size_t)(n + 4) * 4;
    int* slocal = (int*)w;    w += (size_t)(n + 4) * 4;
    int* bsum   = (int*)w;    w += 1024;
    int* bpre   = (int*)w;    w += 1024;
    int* ccol   = (int*)w;    w += (size_t)e * 4;
    float* cval = (float*)w;  w += (size_t)e * 4;

    // ---- CSR build (once; edges constant across layers) ----
    hipMemsetAsync(deg, 0, (size_t)n * 4, stream);
    hist_k<<<(e + 255) / 256, 256, 0, stream>>>(erow, deg, e);
    scan1_k<<<nscan, 256, 0, stream>>>(deg, slocal, bsum, n);
    scan2_k<<<1, 256, 0, stream>>>(bsum, bpre, nscan, rowptr, n);
    scan3_k<<<nscan, 256, 0, stream>>>(slocal, bpre, rowptr, cursor, n);
    scatter_k<<<(e + 255) / 256, 256, 0, stream>>>(erow, ecol, evalv, cursor, ccol, cval, e);

    // ---- BatchNorm stats + fused BN + fc_in GEMM ----
    col_reduce_k<<<NB, 256, 0, stream>>>(x_in, n, PSUM, PSQ);
    finalize_k<true><<<1, 1024, 0, stream>>>(PSUM, PSQ, NB, n, gamma, beta, AB);
    const int gblocks = (n + 31) / 32;
    gemm_k128<DD, true, true><<<gblocks, 256, 0, stream>>>(x_in, fc_in_w, fc_in_b, AB, X, n);

    // ---- 4 GCN layers ----
    for (int l = 0; l < 4; l++) {
        gemm_k128<DD, false, false><<<gblocks, 256, 0, stream>>>(
            X, gc_w + (size_t)l * DD * DD, nullptr, nullptr, Hb, n);
        spmm_csr_k<<<((size_t)n * 32 + 255) / 256, 256, 0, stream>>>(rowptr, ccol, cval, Hb, AGG, n);
        col_reduce_k<<<NB, 256, 0, stream>>>(AGG, n, PSUM, PSQ);
        finalize_k<false><<<1, 1024, 0, stream>>>(PSUM, PSQ, NB, n, nullptr, nullptr, AB);
        pn_apply_k<<<2048, 256, 0, stream>>>(AGG, AB, X, n * DD / 4, l > 0 ? 1 : 0);
    }

    // ---- fc_out ----
    gemm_k128<40, false, true><<<gblocks, 256, 0, stream>>>(X, fc_out_w, fc_out_b, nullptr, out, n);
}

// Round 5
// 596.439 us; speedup vs baseline: 7.4130x; 1.3186x over previous
//
#include <hip/hip_runtime.h>
#include <hip/hip_bf16.h>

// DeepGCN forward: BN -> fc_in -> 4x[GEMM -> SpMM -> PairNorm -> ReLU -> residual] -> fc_out
// R1: bounded unroll in GEMM k-loop (spill fix). R2: parallel finalize. R3: multi-block scan.
// R4: bf16 Hb (halves spmm gather traffic) + MFMA bf16 GEMMs for fc_in + 4 layers.
//     Residual stream X, AGG, all stats/reductions, fc_out stay fp32.

constexpr int DD = 128;

struct alignas(16) f4 { float v[4]; };
typedef unsigned short ushort;
typedef unsigned int uint;
typedef short short8 __attribute__((ext_vector_type(8)));
typedef float f32x4 __attribute__((ext_vector_type(4)));

__device__ inline ushort f2bf(float f) {   // RNE f32->bf16 (no NaN concerns here)
    uint u = __float_as_uint(f);
    u += 0x7fffu + ((u >> 16) & 1u);
    return (ushort)(u >> 16);
}

// ---------------- column reduce: per-block partial colsum/colsumsq ----------------
__global__ __launch_bounds__(256) void col_reduce_k(const float* __restrict__ X, int n,
    float* __restrict__ psum, float* __restrict__ psq)
{
    int c = threadIdx.x & (DD - 1);
    int half = threadIdx.x >> 7;
    int rows_per_blk = (n + gridDim.x - 1) / gridDim.x;
    int r0 = blockIdx.x * rows_per_blk;
    int r1 = min(n, r0 + rows_per_blk);
    float s = 0.f, ss = 0.f;
    for (int r = r0 + half; r < r1; r += 2) {
        float v = X[(size_t)r * DD + c];
        s += v; ss += v * v;
    }
    __shared__ float ls[256], lq[256];
    ls[threadIdx.x] = s; lq[threadIdx.x] = ss;
    __syncthreads();
    if (half == 0) {
        psum[blockIdx.x * DD + c] = ls[c] + ls[c + 128];
        psq [blockIdx.x * DD + c] = lq[c] + lq[c + 128];
    }
}

// ---------------- finalize (BN or PN) ----------------
template<bool BN>
__global__ __launch_bounds__(1024) void finalize_k(const float* __restrict__ psum,
    const float* __restrict__ psq, int nblk, int n,
    const float* __restrict__ gamma, const float* __restrict__ beta,
    float* __restrict__ AB)
{
    const int c = threadIdx.x & (DD - 1);
    const int g = threadIdx.x >> 7;   // 0..7
    float s = 0.f, ss = 0.f;
    for (int b = g; b < nblk; b += 8) {
        s  += psum[b * DD + c];
        ss += psq [b * DD + c];
    }
    __shared__ float Ls[8][DD], Lq[8][DD];
    Ls[g][c] = s; Lq[g][c] = ss;
    __syncthreads();
    float ts = 0.f, tss = 0.f;
    #pragma unroll
    for (int k = 0; k < 8; k++) { ts += Ls[k][c]; tss += Lq[k][c]; }
    float mu = ts / (float)n;
    if (BN) {
        if (threadIdx.x < DD) {
            float var = tss / (float)n - mu * mu;
            float a = gamma[c] * rsqrtf(var + 1e-5f);
            AB[c] = a;
            AB[DD + c] = beta[c] - mu * a;
        }
    } else {
        float cent = tss - (float)n * mu * mu;
        __syncthreads();
        if (g == 0) Ls[0][c] = cent;
        __syncthreads();
        for (int off = 64; off > 0; off >>= 1) {
            if (threadIdx.x < off) Ls[0][threadIdx.x] += Ls[0][threadIdx.x + off];
            __syncthreads();
        }
        if (threadIdx.x < DD) {
            float inv = rsqrtf(1e-6f + Ls[0][0] / (float)n);
            AB[c] = inv;
            AB[DD + c] = -mu * inv;
        }
    }
}

// ---------------- weight pre-transpose: Wt[n][k] = bf16(W[k][n]) ----------------
__global__ __launch_bounds__(256) void wtrans_k(const float* __restrict__ Wsrc,
    ushort* __restrict__ Wt)
{
    // grid: nw*16 blocks; 32x32 tile per block
    int b = blockIdx.x;
    int w = b >> 4, tile = b & 15;
    int tr = (tile >> 2) * 32, tc = (tile & 3) * 32;
    const float* W = Wsrc + (size_t)w * DD * DD;
    ushort* Wo = Wt + (size_t)w * DD * DD;
    __shared__ float tls[32][33];
    int tx = threadIdx.x & 31, ty = threadIdx.x >> 5;  // 32 x 8
    #pragma unroll
    for (int j = 0; j < 32; j += 8)
        tls[ty + j][tx] = W[(size_t)(tr + ty + j) * DD + tc + tx];
    __syncthreads();
    #pragma unroll
    for (int j = 0; j < 32; j += 8)
        Wo[(size_t)(tc + ty + j) * DD + (tr + tx)] = f2bf(tls[tx][ty + j]);
}

// ---------------- MFMA GEMM: Y[n,128] = X[n,128] @ W  (W given as Wt[n][k] bf16) ----
// INSCALE: x -> x*A[k]+B[k] while staging (fused BN). OUTBF: write bf16 (Hb) else f32.
template<bool INSCALE, bool BIAS, bool OUTBF>
__global__ __launch_bounds__(256) void gemm_mfma_k(const float* __restrict__ X,
    const ushort* __restrict__ Wt, const float* __restrict__ AB,
    const float* __restrict__ bias, void* __restrict__ Yout, int n)
{
    __shared__ short xs[64][136];    // [m][k] bf16, pad 136 (272B rows, 16B aligned)
    __shared__ short ws[128][136];   // [n][k] bf16
    __shared__ float ab_s[2 * DD];
    __shared__ float bias_s[DD];
    const int t = threadIdx.x;
    if (INSCALE) ab_s[t] = AB[t];
    if (BIAS && t < DD) bias_s[t] = bias[t];

    const int row0 = blockIdx.x * 64;
    // stage X tile (64 rows x 128 k), f32 -> bf16
    for (int i = t; i < 64 * 32; i += 256) {
        int m = i >> 5, koff = (i & 31) << 2;
        int r = row0 + m;
        f4 v; v.v[0] = v.v[1] = v.v[2] = v.v[3] = 0.f;
        if (r < n) v = *reinterpret_cast<const f4*>(X + (size_t)r * DD + koff);
        if (INSCALE) {
            #pragma unroll
            for (int j = 0; j < 4; j++) v.v[j] = v.v[j] * AB[koff + j] + AB[DD + koff + j];
        }
        uint2 p;
        p.x = (uint)f2bf(v.v[0]) | ((uint)f2bf(v.v[1]) << 16);
        p.y = (uint)f2bf(v.v[2]) | ((uint)f2bf(v.v[3]) << 16);
        *reinterpret_cast<uint2*>(&xs[m][koff]) = p;
    }
    // stage Wt (bf16 linear -> padded LDS)
    for (int i = t; i < 2048; i += 256) {
        int nn = i >> 4, koff = (i & 15) << 3;
        *reinterpret_cast<uint4*>(&ws[nn][koff]) =
            *reinterpret_cast<const uint4*>(Wt + (size_t)nn * DD + koff);
    }
    __syncthreads();

    const int wave = t >> 6, lane = t & 63, fr = lane & 15, g = lane >> 4;
    f32x4 acc[8];
    #pragma unroll
    for (int c = 0; c < 8; c++) acc[c] = (f32x4){0.f, 0.f, 0.f, 0.f};

    #pragma unroll 2
    for (int ks = 0; ks < 4; ks++) {
        int k0 = ks * 32 + g * 8;
        short8 a = *reinterpret_cast<const short8*>(&xs[wave * 16 + fr][k0]);
        #pragma unroll
        for (int c = 0; c < 8; c++) {
            short8 b = *reinterpret_cast<const short8*>(&ws[c * 16 + fr][k0]);
            // mfma(W_frag, X_frag): out lane&15 = X-row (m), g*4+reg = W-col (n)
            acc[c] = __builtin_amdgcn_mfma_f32_16x16x32_bf16(b, a, acc[c], 0, 0, 0);
        }
    }

    const int row = row0 + wave * 16 + fr;
    if (row < n) {
        #pragma unroll
        for (int c = 0; c < 8; c++) {
            int n0 = c * 16 + g * 4;
            if (OUTBF) {
                uint2 o;
                o.x = (uint)f2bf(acc[c][0]) | ((uint)f2bf(acc[c][1]) << 16);
                o.y = (uint)f2bf(acc[c][2]) | ((uint)f2bf(acc[c][3]) << 16);
                *reinterpret_cast<uint2*>((ushort*)Yout + (size_t)row * DD + n0) = o;
            } else {
                f4 o;
                #pragma unroll
                for (int j = 0; j < 4; j++)
                    o.v[j] = acc[c][j] + (BIAS ? bias_s[n0 + j] : 0.f);
                *reinterpret_cast<f4*>((float*)Yout + (size_t)row * DD + n0) = o;
            }
        }
    }
}

// ---------------- fp32 GEMM (fc_out only, NCOL=40) ----------------
template<int NCOL, bool BIAS>
__global__ __launch_bounds__(256) void gemm_k128(const float* __restrict__ X,
    const float* __restrict__ W, const float* __restrict__ bias,
    float* __restrict__ Y, int n)
{
    __shared__ float xs[32][DD];
    __shared__ float ws[DD][NCOL];
    const int t = threadIdx.x;
    {
        const f4* Wv = reinterpret_cast<const f4*>(W);
        f4* wsv = reinterpret_cast<f4*>(&ws[0][0]);
        for (int i = t; i < DD * NCOL / 4; i += 256) wsv[i] = Wv[i];
    }
    const int row0 = blockIdx.x * 32;
    for (int i = t; i < 32 * DD / 4; i += 256) {
        int r = i >> 5;
        int k = (i & 31) << 2;
        f4 v; v.v[0] = v.v[1] = v.v[2] = v.v[3] = 0.f;
        if (row0 + r < n) v = *reinterpret_cast<const f4*>(X + (size_t)(row0 + r) * DD + k);
        *reinterpret_cast<f4*>(&xs[r][k]) = v;
    }
    __syncthreads();

    constexpr int TC = 16;
    constexpr int TR = 256 / TC;
    constexpr int RPT = 32 / TR;
    const int tc = t % TC, tr = t / TC;
    const int c0 = tc * 4;
    const int r0 = tr * RPT;
    if (c0 < NCOL) {
        float acc[RPT][4];
        #pragma unroll
        for (int i = 0; i < RPT; i++)
            #pragma unroll
            for (int j = 0; j < 4; j++) acc[i][j] = 0.f;
        #pragma unroll 2
        for (int k0 = 0; k0 < DD; k0 += 4) {
            f4 a[RPT], w[4];
            #pragma unroll
            for (int i = 0; i < RPT; i++) a[i] = *reinterpret_cast<const f4*>(&xs[r0 + i][k0]);
            #pragma unroll
            for (int q = 0; q < 4; q++) w[q] = *reinterpret_cast<const f4*>(&ws[k0 + q][c0]);
            #pragma unroll
            for (int i = 0; i < RPT; i++)
                #pragma unroll
                for (int q = 0; q < 4; q++)
                    #pragma unroll
                    for (int j = 0; j < 4; j++)
                        acc[i][j] = fmaf(a[i].v[q], w[q].v[j], acc[i][j]);
        }
        #pragma unroll
        for (int i = 0; i < RPT; i++) {
            int r = row0 + r0 + i;
            if (r < n) {
                f4 o;
                #pragma unroll
                for (int j = 0; j < 4; j++) o.v[j] = acc[i][j] + (BIAS ? bias[c0 + j] : 0.f);
                *reinterpret_cast<f4*>(Y + (size_t)r * NCOL + c0) = o;
            }
        }
    }
}

// ---------------- CSR build ----------------
__global__ __launch_bounds__(256) void hist_k(const int* __restrict__ erow,
    int* __restrict__ deg, int e)
{
    int i = blockIdx.x * 256 + threadIdx.x;
    if (i < e) atomicAdd(&deg[erow[i]], 1);
}

constexpr int SCAN_TILE = 1024;

__global__ __launch_bounds__(256) void scan1_k(const int* __restrict__ deg,
    int* __restrict__ local, int* __restrict__ bsum, int n)
{
    const int t = threadIdx.x;
    const int base = blockIdx.x * SCAN_TILE + t * 4;
    int v0 = 0, v1 = 0, v2 = 0, v3 = 0;
    if (base + 3 < n) {
        int4 v = *reinterpret_cast<const int4*>(deg + base);
        v0 = v.x; v1 = v.y; v2 = v.z; v3 = v.w;
    } else {
        if (base + 0 < n) v0 = deg[base + 0];
        if (base + 1 < n) v1 = deg[base + 1];
        if (base + 2 < n) v2 = deg[base + 2];
        if (base + 3 < n) v3 = deg[base + 3];
    }
    int s = v0 + v1 + v2 + v3;
    __shared__ int ps[256];
    ps[t] = s;
    __syncthreads();
    for (int off = 1; off < 256; off <<= 1) {
        int add = (t >= off) ? ps[t - off] : 0;
        __syncthreads();
        ps[t] += add;
        __syncthreads();
    }
    int excl = (t > 0) ? ps[t - 1] : 0;
    int o0 = excl, o1 = excl + v0, o2 = o1 + v1, o3 = o2 + v2;
    if (base + 3 < n) {
        int4 o; o.x = o0; o.y = o1; o.z = o2; o.w = o3;
        *reinterpret_cast<int4*>(local + base) = o;
    } else {
        if (base + 0 < n) local[base + 0] = o0;
        if (base + 1 < n) local[base + 1] = o1;
        if (base + 2 < n) local[base + 2] = o2;
        if (base + 3 < n) local[base + 3] = o3;
    }
    if (t == 255) bsum[blockIdx.x] = ps[255];
}

__global__ __launch_bounds__(256) void scan2_k(const int* __restrict__ bsum,
    int* __restrict__ bpre, int nb, int* __restrict__ rowptr, int n)
{
    const int t = threadIdx.x;
    __shared__ int ps[256];
    ps[t] = (t < nb) ? bsum[t] : 0;
    __syncthreads();
    for (int off = 1; off < 256; off <<= 1) {
        int add = (t >= off) ? ps[t - off] : 0;
        __syncthreads();
        ps[t] += add;
        __syncthreads();
    }
    if (t < nb) bpre[t] = (t > 0) ? ps[t - 1] : 0;
    if (t == 255) rowptr[n] = ps[255];
}

__global__ __launch_bounds__(256) void scan3_k(const int* __restrict__ local,
    const int* __restrict__ bpre, int* __restrict__ rowptr, int* __restrict__ cursor, int n)
{
    const int base = blockIdx.x * SCAN_TILE + threadIdx.x * 4;
    const int p = bpre[blockIdx.x];
    if (base + 3 < n) {
        int4 v = *reinterpret_cast<const int4*>(local + base);
        v.x += p; v.y += p; v.z += p; v.w += p;
        *reinterpret_cast<int4*>(rowptr + base) = v;
        *reinterpret_cast<int4*>(cursor + base) = v;
    } else {
        #pragma unroll
        for (int j = 0; j < 4; j++)
            if (base + j < n) {
                int v = local[base + j] + p;
                rowptr[base + j] = v;
                cursor[base + j] = v;
            }
    }
}

__global__ __launch_bounds__(256) void scatter_k(const int* __restrict__ erow,
    const int* __restrict__ ecol, const float* __restrict__ evalv,
    int* __restrict__ cursor, int* __restrict__ ccol, float* __restrict__ cval, int e)
{
    int i = blockIdx.x * 256 + threadIdx.x;
    if (i >= e) return;
    int r = erow[i];
    int p = atomicAdd(&cursor[r], 1);
    ccol[p] = ecol[i];
    cval[p] = evalv[i];
}

// ---------------- SpMM (CSR gather, bf16 H): AGG[r,:] = sum val * H[col,:] ----------
__global__ __launch_bounds__(256) void spmm_bf16_k(const int* __restrict__ rowptr,
    const int* __restrict__ ccol, const float* __restrict__ cval,
    const ushort* __restrict__ H, float* __restrict__ AGG, int n)
{
    int gid = blockIdx.x * 256 + threadIdx.x;
    int r = gid >> 4;          // 16 threads per row
    int q = gid & 15;          // 8 bf16 each (16B)
    if (r >= n) return;
    int p0 = rowptr[r], p1 = rowptr[r + 1];
    float a0 = 0.f, a1 = 0.f, a2 = 0.f, a3 = 0.f, a4 = 0.f, a5 = 0.f, a6 = 0.f, a7 = 0.f;
    const ushort* Hq = H + q * 8;
    for (int p = p0; p < p1; p++) {
        int c = ccol[p];
        float v = cval[p];
        uint4 u = *reinterpret_cast<const uint4*>(Hq + (size_t)c * DD);
        a0 = fmaf(v, __uint_as_float(u.x << 16), a0);
        a1 = fmaf(v, __uint_as_float(u.x & 0xffff0000u), a1);
        a2 = fmaf(v, __uint_as_float(u.y << 16), a2);
        a3 = fmaf(v, __uint_as_float(u.y & 0xffff0000u), a3);
        a4 = fmaf(v, __uint_as_float(u.z << 16), a4);
        a5 = fmaf(v, __uint_as_float(u.z & 0xffff0000u), a5);
        a6 = fmaf(v, __uint_as_float(u.w << 16), a6);
        a7 = fmaf(v, __uint_as_float(u.w & 0xffff0000u), a7);
    }
    float* o = AGG + (size_t)r * DD + q * 8;
    f4 lo; lo.v[0] = a0; lo.v[1] = a1; lo.v[2] = a2; lo.v[3] = a3;
    f4 hi; hi.v[0] = a4; hi.v[1] = a5; hi.v[2] = a6; hi.v[3] = a7;
    *reinterpret_cast<f4*>(o) = lo;
    *reinterpret_cast<f4*>(o + 4) = hi;
}

// ---------------- PairNorm apply + ReLU + residual (in place on X) ----------------
__global__ __launch_bounds__(256) void pn_apply_k(const float* __restrict__ AGG,
    const float* __restrict__ AB, float* __restrict__ Xio, int total4, int add_old)
{
    int idx = blockIdx.x * 256 + threadIdx.x;
    for (; idx < total4; idx += gridDim.x * 256) {
        int i = idx * 4;
        int c = i & (DD - 1);
        f4 h = *reinterpret_cast<const f4*>(AGG + i);
        f4 o;
        #pragma unroll
        for (int j = 0; j < 4; j++) o.v[j] = fmaxf(h.v[j] * AB[c + j] + AB[DD + c + j], 0.f);
        if (add_old) {
            f4 x = *reinterpret_cast<const f4*>(Xio + i);
            #pragma unroll
            for (int j = 0; j < 4; j++) o.v[j] += x.v[j];
        }
        *reinterpret_cast<f4*>(Xio + i) = o;
    }
}

extern "C" void kernel_launch(void* const* d_in, const int* in_sizes, int n_in,
                              void* d_out, int out_size, void* d_ws, size_t ws_size,
                              hipStream_t stream)
{
    const float* x_in     = (const float*)d_in[0];
    const int*   erow     = (const int*)d_in[1];
    const int*   ecol     = (const int*)d_in[2];
    const float* evalv    = (const float*)d_in[3];
    const float* gamma    = (const float*)d_in[4];
    const float* beta     = (const float*)d_in[5];
    const float* fc_in_w  = (const float*)d_in[6];
    const float* fc_in_b  = (const float*)d_in[7];
    const float* gc_w     = (const float*)d_in[8];
    // d_in[9] = gc_b: no-op under PairNorm (column-mean subtraction cancels it)
    const float* fc_out_w = (const float*)d_in[10];
    const float* fc_out_b = (const float*)d_in[11];
    float* out = (float*)d_out;

    const int n = in_sizes[0] / DD;   // 50000
    const int e = in_sizes[1];        // 800000
    const int NB = 512;
    const int nscan = (n + SCAN_TILE - 1) / SCAN_TILE;

    char* w = (char*)d_ws;
    float* X     = (float*)w;   w += (size_t)n * DD * 4;
    ushort* Hb   = (ushort*)w;  w += (size_t)n * DD * 2;
    float* AGG   = (float*)w;   w += (size_t)n * DD * 4;
    float* PSUM  = (float*)w;   w += (size_t)NB * DD * 4;
    float* PSQ   = (float*)w;   w += (size_t)NB * DD * 4;
    float* AB    = (float*)w;   w += 2 * DD * 4;
    ushort* Wt   = (ushort*)w;  w += (size_t)5 * DD * DD * 2;   // fc_in + 4 layer weights, bf16 [n][k]
    int* deg     = (int*)w;     w += (size_t)(n + 4) * 4;
    int* rowptr  = (int*)w;     w += (size_t)(n + 4) * 4;
    int* cursor  = (int*)w;     w += (size_t)(n + 4) * 4;
    int* slocal  = (int*)w;     w += (size_t)(n + 4) * 4;
    int* bsum    = (int*)w;     w += 1024;
    int* bpre    = (int*)w;     w += 1024;
    int* ccol    = (int*)w;     w += (size_t)e * 4;
    float* cval  = (float*)w;   w += (size_t)e * 4;

    // ---- CSR build (once; edges constant across layers) ----
    hipMemsetAsync(deg, 0, (size_t)n * 4, stream);
    hist_k<<<(e + 255) / 256, 256, 0, stream>>>(erow, deg, e);
    scan1_k<<<nscan, 256, 0, stream>>>(deg, slocal, bsum, n);
    scan2_k<<<1, 256, 0, stream>>>(bsum, bpre, nscan, rowptr, n);
    scan3_k<<<nscan, 256, 0, stream>>>(slocal, bpre, rowptr, cursor, n);
    scatter_k<<<(e + 255) / 256, 256, 0, stream>>>(erow, ecol, evalv, cursor, ccol, cval, e);

    // ---- weight pre-transpose to bf16 Wt[n][k] ----
    wtrans_k<<<16, 256, 0, stream>>>(fc_in_w, Wt);
    wtrans_k<<<64, 256, 0, stream>>>(gc_w, Wt + (size_t)DD * DD);

    // ---- BatchNorm stats + fused BN + fc_in MFMA GEMM (f32 out -> X) ----
    col_reduce_k<<<NB, 256, 0, stream>>>(x_in, n, PSUM, PSQ);
    finalize_k<true><<<1, 1024, 0, stream>>>(PSUM, PSQ, NB, n, gamma, beta, AB);
    const int gblocks64 = (n + 63) / 64;
    gemm_mfma_k<true, true, false><<<gblocks64, 256, 0, stream>>>(
        x_in, Wt, AB, fc_in_b, X, n);

    // ---- 4 GCN layers ----
    for (int l = 0; l < 4; l++) {
        gemm_mfma_k<false, false, true><<<gblocks64, 256, 0, stream>>>(
            X, Wt + (size_t)(1 + l) * DD * DD, nullptr, nullptr, Hb, n);
        spmm_bf16_k<<<((size_t)n * 16 + 255) / 256, 256, 0, stream>>>(
            rowptr, ccol, cval, Hb, AGG, n);
        col_reduce_k<<<NB, 256, 0, stream>>>(AGG, n, PSUM, PSQ);
        finalize_k<false><<<1, 1024, 0, stream>>>(PSUM, PSQ, NB, n, nullptr, nullptr, AB);
        pn_apply_k<<<2048, 256, 0, stream>>>(AGG, AB, X, n * DD / 4, l > 0 ? 1 : 0);
    }

    // ---- fc_out (fp32) ----
    gemm_k128<40, true><<<(n + 31) / 32, 256, 0, stream>>>(X, fc_out_w, fc_out_b, out, n);
}

// Round 6
// 444.878 us; speedup vs baseline: 9.9385x; 1.3407x over previous
//
#include <hip/hip_runtime.h>
#include <hip/hip_bf16.h>

// DeepGCN forward, fully restructured:
//   CSR build (paired int2 payload) -> BN stats ->
//   L0 GEMM from x_in with composite weight (W_in@W0) and composite bias (b@W0) ->
//   4x [ spmm(+fused column s/ss stats) -> finalize(PN) -> next GEMM with fused
//        PN-affine+ReLU+residual pre-stage ] -> fc_out MFMA GEMM (48-col padded).
// R1 spill fix; R2 parallel finalize; R3 multi-block scan; R4 bf16+MFMA;
// R5 paired scatter, spmm-stats fusion, PN fusion into GEMM staging, fc_in elimination.

constexpr int DD = 128;

struct alignas(16) f4 { float v[4]; };
typedef unsigned short ushort;
typedef unsigned int uint;
typedef short short8 __attribute__((ext_vector_type(8)));
typedef float f32x4 __attribute__((ext_vector_type(4)));

__device__ inline ushort f2bf(float f) {   // RNE f32->bf16
    uint u = __float_as_uint(f);
    u += 0x7fffu + ((u >> 16) & 1u);
    return (ushort)(u >> 16);
}

// ---------------- column reduce (BN stats over x_in) ----------------
__global__ __launch_bounds__(256) void col_reduce_k(const float* __restrict__ X, int n,
    float* __restrict__ psum, float* __restrict__ psq)
{
    int c = threadIdx.x & (DD - 1);
    int half = threadIdx.x >> 7;
    int rows_per_blk = (n + gridDim.x - 1) / gridDim.x;
    int r0 = blockIdx.x * rows_per_blk;
    int r1 = min(n, r0 + rows_per_blk);
    float s = 0.f, ss = 0.f;
    for (int r = r0 + half; r < r1; r += 2) {
        float v = X[(size_t)r * DD + c];
        s += v; ss += v * v;
    }
    __shared__ float ls[256], lq[256];
    ls[threadIdx.x] = s; lq[threadIdx.x] = ss;
    __syncthreads();
    if (half == 0) {
        psum[blockIdx.x * DD + c] = ls[c] + ls[c + 128];
        psq [blockIdx.x * DD + c] = lq[c] + lq[c + 128];
    }
}

// ---------------- finalize (BN or PN) ----------------
template<bool BN>
__global__ __launch_bounds__(1024) void finalize_k(const float* __restrict__ psum,
    const float* __restrict__ psq, int nblk, int n,
    const float* __restrict__ gamma, const float* __restrict__ beta,
    float* __restrict__ AB)
{
    const int c = threadIdx.x & (DD - 1);
    const int g = threadIdx.x >> 7;   // 0..7
    float s = 0.f, ss = 0.f;
    for (int b = g; b < nblk; b += 8) {
        s  += psum[b * DD + c];
        ss += psq [b * DD + c];
    }
    __shared__ float Ls[8][DD], Lq[8][DD];
    Ls[g][c] = s; Lq[g][c] = ss;
    __syncthreads();
    float ts = 0.f, tss = 0.f;
    #pragma unroll
    for (int k = 0; k < 8; k++) { ts += Ls[k][c]; tss += Lq[k][c]; }
    float mu = ts / (float)n;
    if (BN) {
        if (threadIdx.x < DD) {
            float var = tss / (float)n - mu * mu;
            float a = gamma[c] * rsqrtf(var + 1e-5f);
            AB[c] = a;
            AB[DD + c] = beta[c] - mu * a;
        }
    } else {
        float cent = tss - (float)n * mu * mu;
        __syncthreads();
        if (g == 0) Ls[0][c] = cent;
        __syncthreads();
        for (int off = 64; off > 0; off >>= 1) {
            if (threadIdx.x < off) Ls[0][threadIdx.x] += Ls[0][threadIdx.x + off];
            __syncthreads();
        }
        if (threadIdx.x < DD) {
            float inv = rsqrtf(1e-6f + Ls[0][0] / (float)n);
            AB[c] = inv;
            AB[DD + c] = -mu * inv;
        }
    }
}

// ---------------- weight transpose 128x128: Wt[n][k] = bf16(W[k][n]) ----------------
__global__ __launch_bounds__(256) void wtrans_k(const float* __restrict__ Wsrc,
    ushort* __restrict__ Wt)
{
    int b = blockIdx.x;
    int w = b >> 4, tile = b & 15;
    int tr = (tile >> 2) * 32, tc = (tile & 3) * 32;
    const float* W = Wsrc + (size_t)w * DD * DD;
    ushort* Wo = Wt + (size_t)w * DD * DD;
    __shared__ float tls[32][33];
    int tx = threadIdx.x & 31, ty = threadIdx.x >> 5;  // 32 x 8
    #pragma unroll
    for (int j = 0; j < 32; j += 8)
        tls[ty + j][tx] = W[(size_t)(tr + ty + j) * DD + tc + tx];
    __syncthreads();
    #pragma unroll
    for (int j = 0; j < 32; j += 8)
        Wo[(size_t)(tc + ty + j) * DD + (tr + tx)] = f2bf(tls[tx][ty + j]);
}

// ---------------- fc_out weight: [128][40] f32 -> [48][128] bf16 (zero-padded) ------
__global__ __launch_bounds__(256) void wtrans_out_k(const float* __restrict__ W,
    ushort* __restrict__ Wt)
{
    for (int i = threadIdx.x; i < 48 * DD; i += 256) {
        int nn = i >> 7, k = i & 127;
        float v = (nn < 40) ? W[(size_t)k * 40 + nn] : 0.f;
        Wt[i] = f2bf(v);
    }
}

// ---------------- composite bias: bc[n] = sum_j b[j] * W0[j][n] ----------------
__global__ __launch_bounds__(128) void bias_comp_k(const float* __restrict__ b,
    const float* __restrict__ W0, float* __restrict__ bc)
{
    int nn = threadIdx.x;
    float acc = 0.f;
    for (int j = 0; j < DD; j++) acc += b[j] * W0[(size_t)j * DD + nn];
    bc[nn] = acc;
}

// ---------------- MFMA GEMM with fused pre-stage ----------------
// PRE: 0=plain f32 read, 1=BN affine (x*A+B), 2=PN relu(x*A+B), 3=PN+residual add
// NCOLF: #16-col fragments (8 -> 128 cols, 3 -> 48 cols padded for 40)
// WRITEX: write the pre-staged f32 x back to Xres (residual stream)
template<int PRE, int NCOLF, int NCOLW, bool BIAS, bool OUTBF, bool WRITEX>
__global__ __launch_bounds__(256) void gemm_mfma_k(const float* __restrict__ IN,
    const ushort* __restrict__ Wt, const float* __restrict__ AB,
    const float* __restrict__ bias, float* __restrict__ Xres,
    void* __restrict__ Yout, int ystride, int n)
{
    __shared__ short xs[64][136];            // [m][k] bf16 (pad 136)
    __shared__ short ws[NCOLF * 16][136];    // [n][k] bf16
    __shared__ float bias_s[DD];
    const int t = threadIdx.x;
    if (BIAS && t < NCOLW) bias_s[t] = bias[t];

    const int row0 = blockIdx.x * 64;
    // pre-stage 64 rows x 128 k: f32 -> (affine/relu/residual) -> bf16 LDS
    for (int i = t; i < 64 * 32; i += 256) {
        int m = i >> 5, koff = (i & 31) << 2;
        int r = row0 + m;
        f4 v; v.v[0] = v.v[1] = v.v[2] = v.v[3] = 0.f;
        if (r < n) {
            v = *reinterpret_cast<const f4*>(IN + (size_t)r * DD + koff);
            if (PRE == 1) {
                #pragma unroll
                for (int j = 0; j < 4; j++) v.v[j] = v.v[j] * AB[koff + j] + AB[DD + koff + j];
            } else if (PRE >= 2) {
                #pragma unroll
                for (int j = 0; j < 4; j++)
                    v.v[j] = fmaxf(v.v[j] * AB[koff + j] + AB[DD + koff + j], 0.f);
                if (PRE == 3) {
                    f4 xo = *reinterpret_cast<const f4*>(Xres + (size_t)r * DD + koff);
                    #pragma unroll
                    for (int j = 0; j < 4; j++) v.v[j] += xo.v[j];
                }
            }
            if (WRITEX)
                *reinterpret_cast<f4*>(Xres + (size_t)r * DD + koff) = v;
        }
        uint2 p;
        p.x = (uint)f2bf(v.v[0]) | ((uint)f2bf(v.v[1]) << 16);
        p.y = (uint)f2bf(v.v[2]) | ((uint)f2bf(v.v[3]) << 16);
        *reinterpret_cast<uint2*>(&xs[m][koff]) = p;
    }
    // stage Wt
    for (int i = t; i < NCOLF * 256; i += 256) {
        int nn = i >> 4, koff = (i & 15) << 3;
        *reinterpret_cast<uint4*>(&ws[nn][koff]) =
            *reinterpret_cast<const uint4*>(Wt + (size_t)nn * DD + koff);
    }
    __syncthreads();

    const int wave = t >> 6, lane = t & 63, fr = lane & 15, g = lane >> 4;
    f32x4 acc[NCOLF];
    #pragma unroll
    for (int c = 0; c < NCOLF; c++) acc[c] = (f32x4){0.f, 0.f, 0.f, 0.f};

    #pragma unroll 2
    for (int ks = 0; ks < 4; ks++) {
        int k0 = ks * 32 + g * 8;
        short8 a = *reinterpret_cast<const short8*>(&xs[wave * 16 + fr][k0]);
        #pragma unroll
        for (int c = 0; c < NCOLF; c++) {
            short8 b = *reinterpret_cast<const short8*>(&ws[c * 16 + fr][k0]);
            // mfma(W_frag, X_frag): out lane&15 = X-row (m), g*4+reg = W-col (n)
            acc[c] = __builtin_amdgcn_mfma_f32_16x16x32_bf16(b, a, acc[c], 0, 0, 0);
        }
    }

    const int row = row0 + wave * 16 + fr;
    if (row < n) {
        #pragma unroll
        for (int c = 0; c < NCOLF; c++) {
            int n0 = c * 16 + g * 4;
            if (OUTBF) {
                float b0 = BIAS ? bias_s[n0 + 0] : 0.f, b1 = BIAS ? bias_s[n0 + 1] : 0.f;
                float b2 = BIAS ? bias_s[n0 + 2] : 0.f, b3 = BIAS ? bias_s[n0 + 3] : 0.f;
                uint2 o;
                o.x = (uint)f2bf(acc[c][0] + b0) | ((uint)f2bf(acc[c][1] + b1) << 16);
                o.y = (uint)f2bf(acc[c][2] + b2) | ((uint)f2bf(acc[c][3] + b3) << 16);
                *reinterpret_cast<uint2*>((ushort*)Yout + (size_t)row * DD + n0) = o;
            } else if (n0 + 3 < NCOLW) {
                f4 o;
                #pragma unroll
                for (int j = 0; j < 4; j++)
                    o.v[j] = acc[c][j] + (BIAS ? bias_s[n0 + j] : 0.f);
                *reinterpret_cast<f4*>((float*)Yout + (size_t)row * ystride + n0) = o;
            }
        }
    }
}

// ---------------- CSR build ----------------
__global__ __launch_bounds__(256) void hist_k(const int* __restrict__ erow,
    int* __restrict__ deg, int e)
{
    int i = blockIdx.x * 256 + threadIdx.x;
    if (i < e) atomicAdd(&deg[erow[i]], 1);
}

constexpr int SCAN_TILE = 1024;

__global__ __launch_bounds__(256) void scan1_k(const int* __restrict__ deg,
    int* __restrict__ local, int* __restrict__ bsum, int n)
{
    const int t = threadIdx.x;
    const int base = blockIdx.x * SCAN_TILE + t * 4;
    int v0 = 0, v1 = 0, v2 = 0, v3 = 0;
    if (base + 3 < n) {
        int4 v = *reinterpret_cast<const int4*>(deg + base);
        v0 = v.x; v1 = v.y; v2 = v.z; v3 = v.w;
    } else {
        if (base + 0 < n) v0 = deg[base + 0];
        if (base + 1 < n) v1 = deg[base + 1];
        if (base + 2 < n) v2 = deg[base + 2];
        if (base + 3 < n) v3 = deg[base + 3];
    }
    int s = v0 + v1 + v2 + v3;
    __shared__ int ps[256];
    ps[t] = s;
    __syncthreads();
    for (int off = 1; off < 256; off <<= 1) {
        int add = (t >= off) ? ps[t - off] : 0;
        __syncthreads();
        ps[t] += add;
        __syncthreads();
    }
    int excl = (t > 0) ? ps[t - 1] : 0;
    int o0 = excl, o1 = excl + v0, o2 = o1 + v1, o3 = o2 + v2;
    if (base + 3 < n) {
        int4 o; o.x = o0; o.y = o1; o.z = o2; o.w = o3;
        *reinterpret_cast<int4*>(local + base) = o;
    } else {
        if (base + 0 < n) local[base + 0] = o0;
        if (base + 1 < n) local[base + 1] = o1;
        if (base + 2 < n) local[base + 2] = o2;
        if (base + 3 < n) local[base + 3] = o3;
    }
    if (t == 255) bsum[blockIdx.x] = ps[255];
}

__global__ __launch_bounds__(256) void scan2_k(const int* __restrict__ bsum,
    int* __restrict__ bpre, int nb, int* __restrict__ rowptr, int n)
{
    const int t = threadIdx.x;
    __shared__ int ps[256];
    ps[t] = (t < nb) ? bsum[t] : 0;
    __syncthreads();
    for (int off = 1; off < 256; off <<= 1) {
        int add = (t >= off) ? ps[t - off] : 0;
        __syncthreads();
        ps[t] += add;
        __syncthreads();
    }
    if (t < nb) bpre[t] = (t > 0) ? ps[t - 1] : 0;
    if (t == 255) rowptr[n] = ps[255];
}

__global__ __launch_bounds__(256) void scan3_k(const int* __restrict__ local,
    const int* __restrict__ bpre, int* __restrict__ rowptr, int* __restrict__ cursor, int n)
{
    const int base = blockIdx.x * SCAN_TILE + threadIdx.x * 4;
    const int p = bpre[blockIdx.x];
    if (base + 3 < n) {
        int4 v = *reinterpret_cast<const int4*>(local + base);
        v.x += p; v.y += p; v.z += p; v.w += p;
        *reinterpret_cast<int4*>(rowptr + base) = v;
        *reinterpret_cast<int4*>(cursor + base) = v;
    } else {
        #pragma unroll
        for (int j = 0; j < 4; j++)
            if (base + j < n) {
                int v = local[base + j] + p;
                rowptr[base + j] = v;
                cursor[base + j] = v;
            }
    }
}

// paired payload: one 8B store per edge (halves dirty-line count vs 2x4B)
__global__ __launch_bounds__(256) void scatter_k(const int* __restrict__ erow,
    const int* __restrict__ ecol, const float* __restrict__ evalv,
    int* __restrict__ cursor, int2* __restrict__ cpair, int e)
{
    int i = blockIdx.x * 256 + threadIdx.x;
    if (i >= e) return;
    int r = erow[i];
    int p = atomicAdd(&cursor[r], 1);
    int2 pr; pr.x = ecol[i]; pr.y = __float_as_int(evalv[i]);
    cpair[p] = pr;
}

// ---------------- SpMM (bf16 gather) + fused column sum/sumsq stats ----------------
// 16 threads/row, 16 rows/block. Column stats: shuffle-reduce 4 rows per wave,
// LDS-combine 4 waves, atomicAdd into 64 global slots.
__global__ __launch_bounds__(256) void spmm_fused_k(const int* __restrict__ rowptr,
    const int2* __restrict__ cpair, const ushort* __restrict__ H,
    float* __restrict__ AGG, float* __restrict__ psum, float* __restrict__ psq, int n)
{
    const int t = threadIdx.x;
    const int gid = blockIdx.x * 256 + t;
    const int r = gid >> 4;
    const int q = t & 15;
    float a[8];
    #pragma unroll
    for (int j = 0; j < 8; j++) a[j] = 0.f;

    if (r < n) {
        int p0 = rowptr[r], p1 = rowptr[r + 1];
        const ushort* Hq = H + q * 8;
        for (int p = p0; p < p1; p++) {
            int2 cv = cpair[p];
            float v = __int_as_float(cv.y);
            uint4 u = *reinterpret_cast<const uint4*>(Hq + (size_t)cv.x * DD);
            a[0] = fmaf(v, __uint_as_float(u.x << 16), a[0]);
            a[1] = fmaf(v, __uint_as_float(u.x & 0xffff0000u), a[1]);
            a[2] = fmaf(v, __uint_as_float(u.y << 16), a[2]);
            a[3] = fmaf(v, __uint_as_float(u.y & 0xffff0000u), a[3]);
            a[4] = fmaf(v, __uint_as_float(u.z << 16), a[4]);
            a[5] = fmaf(v, __uint_as_float(u.z & 0xffff0000u), a[5]);
            a[6] = fmaf(v, __uint_as_float(u.w << 16), a[6]);
            a[7] = fmaf(v, __uint_as_float(u.w & 0xffff0000u), a[7]);
        }
        float* o = AGG + (size_t)r * DD + q * 8;
        f4 lo; lo.v[0] = a[0]; lo.v[1] = a[1]; lo.v[2] = a[2]; lo.v[3] = a[3];
        f4 hi; hi.v[0] = a[4]; hi.v[1] = a[5]; hi.v[2] = a[6]; hi.v[3] = a[7];
        *reinterpret_cast<f4*>(o) = lo;
        *reinterpret_cast<f4*>(o + 4) = hi;
    }

    // column stats: reduce the 4 rows within each wave (lane bits 4..5)
    float s[8], sq[8];
    #pragma unroll
    for (int j = 0; j < 8; j++) { s[j] = a[j]; sq[j] = a[j] * a[j]; }
    #pragma unroll
    for (int j = 0; j < 8; j++) {
        s[j]  += __shfl_xor(s[j], 16);  sq[j] += __shfl_xor(sq[j], 16);
        s[j]  += __shfl_xor(s[j], 32);  sq[j] += __shfl_xor(sq[j], 32);
    }
    __shared__ float sA[4][DD], qA[4][DD];
    const int wave = t >> 6, lane = t & 63;
    if (lane < 16) {
        #pragma unroll
        for (int j = 0; j < 8; j++) {
            sA[wave][lane * 8 + j] = s[j];
            qA[wave][lane * 8 + j] = sq[j];
        }
    }
    __syncthreads();
    if (t < DD) {
        float S = 0.f, Q = 0.f;
        #pragma unroll
        for (int w = 0; w < 4; w++) { S += sA[w][t]; Q += qA[w][t]; }
        int slot = (blockIdx.x & 63) * DD + t;
        atomicAdd(&psum[slot], S);
        atomicAdd(&psq[slot], Q);
    }
}

extern "C" void kernel_launch(void* const* d_in, const int* in_sizes, int n_in,
                              void* d_out, int out_size, void* d_ws, size_t ws_size,
                              hipStream_t stream)
{
    const float* x_in     = (const float*)d_in[0];
    const int*   erow     = (const int*)d_in[1];
    const int*   ecol     = (const int*)d_in[2];
    const float* evalv    = (const float*)d_in[3];
    const float* gamma    = (const float*)d_in[4];
    const float* beta     = (const float*)d_in[5];
    const float* fc_in_w  = (const float*)d_in[6];
    const float* fc_in_b  = (const float*)d_in[7];
    const float* gc_w     = (const float*)d_in[8];
    // d_in[9] = gc_b: no-op under PairNorm (column-mean subtraction cancels it)
    const float* fc_out_w = (const float*)d_in[10];
    const float* fc_out_b = (const float*)d_in[11];
    float* out = (float*)d_out;

    const int n = in_sizes[0] / DD;   // 50000
    const int e = in_sizes[1];        // 800000
    const int NB = 512;
    const int nscan = (n + SCAN_TILE - 1) / SCAN_TILE;

    char* w = (char*)d_ws;
    float* X      = (float*)w;   w += (size_t)n * DD * 4;
    ushort* Hb    = (ushort*)w;  w += (size_t)n * DD * 2;
    float* AGG    = (float*)w;   w += (size_t)n * DD * 4;
    float* PSUM   = (float*)w;   w += (size_t)NB * DD * 4;    // BN partials
    float* PSQ    = (float*)w;   w += (size_t)NB * DD * 4;
    float* PSUMS  = (float*)w;   w += (size_t)64 * DD * 4;    // PN atomic slots
    float* PSQS   = (float*)w;   w += (size_t)64 * DD * 4;
    float* AB     = (float*)w;   w += 2 * DD * 4;
    ushort* Wt    = (ushort*)w;  w += (size_t)4 * DD * DD * 2; // gc_w bf16 [n][k]
    ushort* Wtc   = (ushort*)w;  w += (size_t)DD * DD * 2;     // composite W_in@W0
    ushort* WtO   = (ushort*)w;  w += (size_t)48 * DD * 2;     // fc_out padded
    float* Ycomp  = (float*)w;   w += (size_t)DD * DD * 4;
    float* bc     = (float*)w;   w += DD * 4;
    int* deg      = (int*)w;     w += (size_t)(n + 4) * 4;
    int* rowptr   = (int*)w;     w += (size_t)(n + 4) * 4;
    int* cursor   = (int*)w;     w += (size_t)(n + 4) * 4;
    int* slocal   = (int*)w;     w += (size_t)(n + 4) * 4;
    int* bsum     = (int*)w;     w += 1024;
    int* bpre     = (int*)w;     w += 1024;
    int2* cpair   = (int2*)w;    w += (size_t)e * 8;

    // ---- CSR build ----
    hipMemsetAsync(deg, 0, (size_t)n * 4, stream);
    hist_k<<<(e + 255) / 256, 256, 0, stream>>>(erow, deg, e);
    scan1_k<<<nscan, 256, 0, stream>>>(deg, slocal, bsum, n);
    scan2_k<<<1, 256, 0, stream>>>(bsum, bpre, nscan, rowptr, n);
    scan3_k<<<nscan, 256, 0, stream>>>(slocal, bpre, rowptr, cursor, n);
    scatter_k<<<(e + 255) / 256, 256, 0, stream>>>(erow, ecol, evalv, cursor, cpair, e);

    // ---- weights: gc_w -> bf16 [n][k]; composite W_in@W0; composite bias; fc_out ----
    wtrans_k<<<64, 256, 0, stream>>>(gc_w, Wt);
    gemm_mfma_k<0, 8, 128, false, false, false><<<2, 256, 0, stream>>>(
        fc_in_w, Wt, nullptr, nullptr, nullptr, Ycomp, DD, DD);          // Ycomp = W_in @ W0
    wtrans_k<<<16, 256, 0, stream>>>(Ycomp, Wtc);
    bias_comp_k<<<1, 128, 0, stream>>>(fc_in_b, gc_w, bc);               // bc = b @ W0
    wtrans_out_k<<<1, 256, 0, stream>>>(fc_out_w, WtO);

    // ---- BN stats ----
    col_reduce_k<<<NB, 256, 0, stream>>>(x_in, n, PSUM, PSQ);
    finalize_k<true><<<1, 1024, 0, stream>>>(PSUM, PSQ, NB, n, gamma, beta, AB);

    const int gblocks64 = (n + 63) / 64;
    const int sblocks = ((size_t)n * 16 + 255) / 256;

    // ---- layer 0: Hb = BN(x_in) @ (W_in@W0) + b@W0 ----
    gemm_mfma_k<1, 8, 128, true, true, false><<<gblocks64, 256, 0, stream>>>(
        x_in, Wtc, AB, bc, nullptr, Hb, DD, n);

    for (int l = 0; l < 4; l++) {
        hipMemsetAsync(PSUMS, 0, (size_t)2 * 64 * DD * 4, stream);   // PSUMS+PSQS
        spmm_fused_k<<<sblocks, 256, 0, stream>>>(rowptr, cpair, Hb, AGG, PSUMS, PSQS, n);
        finalize_k<false><<<1, 1024, 0, stream>>>(PSUMS, PSQS, 64, n, nullptr, nullptr, AB);
        if (l < 3) {
            // next-layer GEMM with fused PN+ReLU(+residual); writes residual stream X
            if (l == 0)
                gemm_mfma_k<2, 8, 128, false, true, true><<<gblocks64, 256, 0, stream>>>(
                    AGG, Wt + (size_t)(l + 1) * DD * DD, AB, nullptr, X, Hb, DD, n);
            else
                gemm_mfma_k<3, 8, 128, false, true, true><<<gblocks64, 256, 0, stream>>>(
                    AGG, Wt + (size_t)(l + 1) * DD * DD, AB, nullptr, X, Hb, DD, n);
        } else {
            // fc_out fused with final PN+ReLU+residual (x4 = relu(pn(AGG3)) + x3)
            gemm_mfma_k<3, 3, 40, true, false, false><<<gblocks64, 256, 0, stream>>>(
                AGG, WtO, AB, fc_out_b, X, out, 40, n);
        }
    }
}

// Round 7
// 419.196 us; speedup vs baseline: 10.5474x; 1.0613x over previous
//
#include <hip/hip_runtime.h>
#include <hip/hip_bf16.h>

// DeepGCN forward, restructured:
//   CSR build (histogram -> 3-phase scan -> 2-pass BINNED scatter) -> BN stats ->
//   L0 GEMM from x_in with composite weight (W_in@W0) + composite bias (b@W0) ->
//   4x [ spmm(bf16 gather + fused column stats, bf16 AGG out) -> finalize(PN) ->
//        next GEMM with fused PN+ReLU+residual pre-stage (bf16 X stream) ] ->
//   fc_out MFMA (48-col padded), fused with final PN+ReLU+residual.
// R5: paired scatter, spmm-stats fusion, PN fusion, fc_in elimination.
// R6: binned 2-pass scatter (random 8B writes -> L2-resident), AGG+X bf16.

constexpr int DD = 128;

struct alignas(16) f4 { float v[4]; };
typedef unsigned short ushort;
typedef unsigned int uint;
typedef short short8 __attribute__((ext_vector_type(8)));
typedef float f32x4 __attribute__((ext_vector_type(4)));

__device__ inline ushort f2bf(float f) {   // RNE f32->bf16
    uint u = __float_as_uint(f);
    u += 0x7fffu + ((u >> 16) & 1u);
    return (ushort)(u >> 16);
}
__device__ inline void bf8_unpack(uint4 u, float* v) {
    v[0] = __uint_as_float(u.x << 16); v[1] = __uint_as_float(u.x & 0xffff0000u);
    v[2] = __uint_as_float(u.y << 16); v[3] = __uint_as_float(u.y & 0xffff0000u);
    v[4] = __uint_as_float(u.z << 16); v[5] = __uint_as_float(u.z & 0xffff0000u);
    v[6] = __uint_as_float(u.w << 16); v[7] = __uint_as_float(u.w & 0xffff0000u);
}
__device__ inline uint4 bf8_pack(const float* v) {
    uint4 o;
    o.x = (uint)f2bf(v[0]) | ((uint)f2bf(v[1]) << 16);
    o.y = (uint)f2bf(v[2]) | ((uint)f2bf(v[3]) << 16);
    o.z = (uint)f2bf(v[4]) | ((uint)f2bf(v[5]) << 16);
    o.w = (uint)f2bf(v[6]) | ((uint)f2bf(v[7]) << 16);
    return o;
}

// ---------------- column reduce (BN stats over x_in) ----------------
__global__ __launch_bounds__(256) void col_reduce_k(const float* __restrict__ X, int n,
    float* __restrict__ psum, float* __restrict__ psq)
{
    int c = threadIdx.x & (DD - 1);
    int half = threadIdx.x >> 7;
    int rows_per_blk = (n + gridDim.x - 1) / gridDim.x;
    int r0 = blockIdx.x * rows_per_blk;
    int r1 = min(n, r0 + rows_per_blk);
    float s = 0.f, ss = 0.f;
    for (int r = r0 + half; r < r1; r += 2) {
        float v = X[(size_t)r * DD + c];
        s += v; ss += v * v;
    }
    __shared__ float ls[256], lq[256];
    ls[threadIdx.x] = s; lq[threadIdx.x] = ss;
    __syncthreads();
    if (half == 0) {
        psum[blockIdx.x * DD + c] = ls[c] + ls[c + 128];
        psq [blockIdx.x * DD + c] = lq[c] + lq[c + 128];
    }
}

// ---------------- finalize (BN or PN) ----------------
template<bool BN>
__global__ __launch_bounds__(1024) void finalize_k(const float* __restrict__ psum,
    const float* __restrict__ psq, int nblk, int n,
    const float* __restrict__ gamma, const float* __restrict__ beta,
    float* __restrict__ AB)
{
    const int c = threadIdx.x & (DD - 1);
    const int g = threadIdx.x >> 7;   // 0..7
    float s = 0.f, ss = 0.f;
    for (int b = g; b < nblk; b += 8) {
        s  += psum[b * DD + c];
        ss += psq [b * DD + c];
    }
    __shared__ float Ls[8][DD], Lq[8][DD];
    Ls[g][c] = s; Lq[g][c] = ss;
    __syncthreads();
    float ts = 0.f, tss = 0.f;
    #pragma unroll
    for (int k = 0; k < 8; k++) { ts += Ls[k][c]; tss += Lq[k][c]; }
    float mu = ts / (float)n;
    if (BN) {
        if (threadIdx.x < DD) {
            float var = tss / (float)n - mu * mu;
            float a = gamma[c] * rsqrtf(var + 1e-5f);
            AB[c] = a;
            AB[DD + c] = beta[c] - mu * a;
        }
    } else {
        float cent = tss - (float)n * mu * mu;
        __syncthreads();
        if (g == 0) Ls[0][c] = cent;
        __syncthreads();
        for (int off = 64; off > 0; off >>= 1) {
            if (threadIdx.x < off) Ls[0][threadIdx.x] += Ls[0][threadIdx.x + off];
            __syncthreads();
        }
        if (threadIdx.x < DD) {
            float inv = rsqrtf(1e-6f + Ls[0][0] / (float)n);
            AB[c] = inv;
            AB[DD + c] = -mu * inv;
        }
    }
}

// ---------------- weight transpose 128x128: Wt[n][k] = bf16(W[k][n]) ----------------
__global__ __launch_bounds__(256) void wtrans_k(const float* __restrict__ Wsrc,
    ushort* __restrict__ Wt)
{
    int b = blockIdx.x;
    int w = b >> 4, tile = b & 15;
    int tr = (tile >> 2) * 32, tc = (tile & 3) * 32;
    const float* W = Wsrc + (size_t)w * DD * DD;
    ushort* Wo = Wt + (size_t)w * DD * DD;
    __shared__ float tls[32][33];
    int tx = threadIdx.x & 31, ty = threadIdx.x >> 5;  // 32 x 8
    #pragma unroll
    for (int j = 0; j < 32; j += 8)
        tls[ty + j][tx] = W[(size_t)(tr + ty + j) * DD + tc + tx];
    __syncthreads();
    #pragma unroll
    for (int j = 0; j < 32; j += 8)
        Wo[(size_t)(tc + ty + j) * DD + (tr + tx)] = f2bf(tls[tx][ty + j]);
}

// ---------------- fc_out weight: [128][40] f32 -> [48][128] bf16 (zero-padded) ------
__global__ __launch_bounds__(256) void wtrans_out_k(const float* __restrict__ W,
    ushort* __restrict__ Wt)
{
    for (int i = threadIdx.x; i < 48 * DD; i += 256) {
        int nn = i >> 7, k = i & 127;
        float v = (nn < 40) ? W[(size_t)k * 40 + nn] : 0.f;
        Wt[i] = f2bf(v);
    }
}

// ---------------- composite bias: bc[n] = sum_j b[j] * W0[j][n] ----------------
__global__ __launch_bounds__(128) void bias_comp_k(const float* __restrict__ b,
    const float* __restrict__ W0, float* __restrict__ bc)
{
    int nn = threadIdx.x;
    float acc = 0.f;
    for (int j = 0; j < DD; j++) acc += b[j] * W0[(size_t)j * DD + nn];
    bc[nn] = acc;
}

// ---------------- MFMA GEMM with fused pre-stage ----------------
// PRE: 0=f32 plain, 1=f32 BN affine, 2=bf16-in PN relu(x*A+B), 3=PN + residual (bf16 X)
// NCOLF: #16-col fragments (8 -> 128 cols, 3 -> 48 padded for 40)
// WRITEX: write pre-staged x (bf16) back to Xres residual stream
template<int PRE, int NCOLF, int NCOLW, bool BIAS, bool OUTBF, bool WRITEX>
__global__ __launch_bounds__(256) void gemm_mfma_k(const void* __restrict__ INv,
    const ushort* __restrict__ Wt, const float* __restrict__ AB,
    const float* __restrict__ bias, void* __restrict__ Xresv,
    void* __restrict__ Yout, int ystride, int n)
{
    __shared__ short xs[64][136];            // [m][k] bf16 (pad 136)
    __shared__ short ws[NCOLF * 16][136];    // [n][k] bf16
    __shared__ float bias_s[DD];
    const int t = threadIdx.x;
    if (BIAS && t < NCOLW) bias_s[t] = bias[t];

    const int row0 = blockIdx.x * 64;
    if (PRE <= 1) {
        const float* IN = (const float*)INv;
        for (int i = t; i < 64 * 32; i += 256) {
            int m = i >> 5, koff = (i & 31) << 2;
            int r = row0 + m;
            f4 v; v.v[0] = v.v[1] = v.v[2] = v.v[3] = 0.f;
            if (r < n) {
                v = *reinterpret_cast<const f4*>(IN + (size_t)r * DD + koff);
                if (PRE == 1) {
                    #pragma unroll
                    for (int j = 0; j < 4; j++) v.v[j] = v.v[j] * AB[koff + j] + AB[DD + koff + j];
                }
            }
            uint2 p;
            p.x = (uint)f2bf(v.v[0]) | ((uint)f2bf(v.v[1]) << 16);
            p.y = (uint)f2bf(v.v[2]) | ((uint)f2bf(v.v[3]) << 16);
            *reinterpret_cast<uint2*>(&xs[m][koff]) = p;
        }
    } else {
        const ushort* IN = (const ushort*)INv;
        ushort* Xres = (ushort*)Xresv;
        for (int i = t; i < 64 * 16; i += 256) {
            int m = i >> 4, k8 = (i & 15) << 3;
            int r = row0 + m;
            float v[8];
            if (r < n) {
                uint4 u = *reinterpret_cast<const uint4*>(IN + (size_t)r * DD + k8);
                bf8_unpack(u, v);
                #pragma unroll
                for (int j = 0; j < 8; j++)
                    v[j] = fmaxf(v[j] * AB[k8 + j] + AB[DD + k8 + j], 0.f);
                if (PRE == 3) {
                    uint4 xo = *reinterpret_cast<const uint4*>(Xres + (size_t)r * DD + k8);
                    float xov[8]; bf8_unpack(xo, xov);
                    #pragma unroll
                    for (int j = 0; j < 8; j++) v[j] += xov[j];
                }
                uint4 pk = bf8_pack(v);
                if (WRITEX)
                    *reinterpret_cast<uint4*>(Xres + (size_t)r * DD + k8) = pk;
                *reinterpret_cast<uint4*>(&xs[m][k8]) = pk;
            } else {
                uint4 z; z.x = z.y = z.z = z.w = 0u;
                *reinterpret_cast<uint4*>(&xs[m][k8]) = z;
            }
        }
    }
    // stage Wt
    for (int i = t; i < NCOLF * 256; i += 256) {
        int nn = i >> 4, koff = (i & 15) << 3;
        *reinterpret_cast<uint4*>(&ws[nn][koff]) =
            *reinterpret_cast<const uint4*>(Wt + (size_t)nn * DD + koff);
    }
    __syncthreads();

    const int wave = t >> 6, lane = t & 63, fr = lane & 15, g = lane >> 4;
    f32x4 acc[NCOLF];
    #pragma unroll
    for (int c = 0; c < NCOLF; c++) acc[c] = (f32x4){0.f, 0.f, 0.f, 0.f};

    #pragma unroll 2
    for (int ks = 0; ks < 4; ks++) {
        int k0 = ks * 32 + g * 8;
        short8 a = *reinterpret_cast<const short8*>(&xs[wave * 16 + fr][k0]);
        #pragma unroll
        for (int c = 0; c < NCOLF; c++) {
            short8 b = *reinterpret_cast<const short8*>(&ws[c * 16 + fr][k0]);
            // mfma(W_frag, X_frag): out lane&15 = X-row (m), g*4+reg = W-col (n)
            acc[c] = __builtin_amdgcn_mfma_f32_16x16x32_bf16(b, a, acc[c], 0, 0, 0);
        }
    }

    const int row = row0 + wave * 16 + fr;
    if (row < n) {
        #pragma unroll
        for (int c = 0; c < NCOLF; c++) {
            int n0 = c * 16 + g * 4;
            if (OUTBF) {
                float b0 = BIAS ? bias_s[n0 + 0] : 0.f, b1 = BIAS ? bias_s[n0 + 1] : 0.f;
                float b2 = BIAS ? bias_s[n0 + 2] : 0.f, b3 = BIAS ? bias_s[n0 + 3] : 0.f;
                uint2 o;
                o.x = (uint)f2bf(acc[c][0] + b0) | ((uint)f2bf(acc[c][1] + b1) << 16);
                o.y = (uint)f2bf(acc[c][2] + b2) | ((uint)f2bf(acc[c][3] + b3) << 16);
                *reinterpret_cast<uint2*>((ushort*)Yout + (size_t)row * DD + n0) = o;
            } else if (n0 + 3 < NCOLW) {
                f4 o;
                #pragma unroll
                for (int j = 0; j < 4; j++)
                    o.v[j] = acc[c][j] + (BIAS ? bias_s[n0 + j] : 0.f);
                *reinterpret_cast<f4*>((float*)Yout + (size_t)row * ystride + n0) = o;
            }
        }
    }
}

// ---------------- CSR build ----------------
__global__ __launch_bounds__(256) void hist_k(const int* __restrict__ erow,
    int* __restrict__ deg, int e)
{
    int i = blockIdx.x * 256 + threadIdx.x;
    if (i < e) atomicAdd(&deg[erow[i]], 1);
}

constexpr int SCAN_TILE = 1024;
constexpr int BSH = 9;                 // 512-row buckets

__global__ __launch_bounds__(256) void scan1_k(const int* __restrict__ deg,
    int* __restrict__ local, int* __restrict__ bsum, int n)
{
    const int t = threadIdx.x;
    const int base = blockIdx.x * SCAN_TILE + t * 4;
    int v0 = 0, v1 = 0, v2 = 0, v3 = 0;
    if (base + 3 < n) {
        int4 v = *reinterpret_cast<const int4*>(deg + base);
        v0 = v.x; v1 = v.y; v2 = v.z; v3 = v.w;
    } else {
        if (base + 0 < n) v0 = deg[base + 0];
        if (base + 1 < n) v1 = deg[base + 1];
        if (base + 2 < n) v2 = deg[base + 2];
        if (base + 3 < n) v3 = deg[base + 3];
    }
    int s = v0 + v1 + v2 + v3;
    __shared__ int ps[256];
    ps[t] = s;
    __syncthreads();
    for (int off = 1; off < 256; off <<= 1) {
        int add = (t >= off) ? ps[t - off] : 0;
        __syncthreads();
        ps[t] += add;
        __syncthreads();
    }
    int excl = (t > 0) ? ps[t - 1] : 0;
    int o0 = excl, o1 = excl + v0, o2 = o1 + v1, o3 = o2 + v2;
    if (base + 3 < n) {
        int4 o; o.x = o0; o.y = o1; o.z = o2; o.w = o3;
        *reinterpret_cast<int4*>(local + base) = o;
    } else {
        if (base + 0 < n) local[base + 0] = o0;
        if (base + 1 < n) local[base + 1] = o1;
        if (base + 2 < n) local[base + 2] = o2;
        if (base + 3 < n) local[base + 3] = o3;
    }
    if (t == 255) bsum[blockIdx.x] = ps[255];
}

__global__ __launch_bounds__(256) void scan2_k(const int* __restrict__ bsum,
    int* __restrict__ bpre, int nb, int* __restrict__ rowptr, int n)
{
    const int t = threadIdx.x;
    __shared__ int ps[256];
    ps[t] = (t < nb) ? bsum[t] : 0;
    __syncthreads();
    for (int off = 1; off < 256; off <<= 1) {
        int add = (t >= off) ? ps[t - off] : 0;
        __syncthreads();
        ps[t] += add;
        __syncthreads();
    }
    if (t < nb) bpre[t] = (t > 0) ? ps[t - 1] : 0;
    if (t == 255) rowptr[n] = ps[255];
}

__global__ __launch_bounds__(256) void scan3_k(const int* __restrict__ local,
    const int* __restrict__ bpre, int* __restrict__ rowptr, int* __restrict__ cursor, int n)
{
    const int base = blockIdx.x * SCAN_TILE + threadIdx.x * 4;
    const int p = bpre[blockIdx.x];
    if (base + 3 < n) {
        int4 v = *reinterpret_cast<const int4*>(local + base);
        v.x += p; v.y += p; v.z += p; v.w += p;
        *reinterpret_cast<int4*>(rowptr + base) = v;
        *reinterpret_cast<int4*>(cursor + base) = v;
    } else {
        #pragma unroll
        for (int j = 0; j < 4; j++)
            if (base + j < n) {
                int v = local[base + j] + p;
                rowptr[base + j] = v;
                cursor[base + j] = v;
            }
    }
}

// gcur[b] = start of bucket b's region in the edge array
__global__ void gcur_init_k(const int* __restrict__ rowptr, int* __restrict__ gcur,
    int n, int nbuk)
{
    int b = threadIdx.x;
    if (b <= nbuk) gcur[b] = rowptr[min(b << BSH, n)];
}

// pass A: bin edges by 512-row bucket (LDS rank; bucket-contiguous 8B writes)
__global__ __launch_bounds__(256) void bin_a_k(const int* __restrict__ erow,
    const int* __restrict__ ecol, const float* __restrict__ evalv,
    int* __restrict__ gcur, uint2* __restrict__ binned, int e)
{
    __shared__ int cnt[128];
    __shared__ int base[128];
    const int t = threadIdx.x;
    if (t < 128) cnt[t] = 0;
    __syncthreads();
    const int i0 = blockIdx.x * 2048 + t * 8;
    int rw[8], cl[8], rk[8];
    float vl[8];
    #pragma unroll
    for (int j = 0; j < 8; j++) {
        int idx = i0 + j;
        if (idx < e) { rw[j] = erow[idx]; cl[j] = ecol[idx]; vl[j] = evalv[idx]; }
        else rw[j] = -1;
    }
    #pragma unroll
    for (int j = 0; j < 8; j++)
        if (rw[j] >= 0) rk[j] = atomicAdd(&cnt[rw[j] >> BSH], 1);
    __syncthreads();
    if (t < 128) base[t] = cnt[t] ? atomicAdd(&gcur[t], cnt[t]) : 0;
    __syncthreads();
    #pragma unroll
    for (int j = 0; j < 8; j++) {
        if (rw[j] >= 0) {
            int b = rw[j] >> BSH, rl = rw[j] & ((1 << BSH) - 1);
            uint2 pr;
            pr.x = (uint)cl[j] | ((uint)rl << 16);
            pr.y = __float_as_uint(vl[j]);
            binned[base[b] + rk[j]] = pr;
        }
    }
}

// pass B: within-bucket scatter to CSR position (dest region ~64KB -> L2-resident)
__global__ __launch_bounds__(256) void bin_b_k(const uint2* __restrict__ binned,
    const int* __restrict__ rowptr, int* __restrict__ cursor,
    int2* __restrict__ cpair, int n)
{
    const int b = blockIdx.x;
    const int r0 = min(b << BSH, n), r1 = min((b + 1) << BSH, n);
    const int p0 = rowptr[r0], p1 = rowptr[r1];
    for (int p = p0 + threadIdx.x; p < p1; p += 256) {
        uint2 u = binned[p];
        int r = (b << BSH) + (int)(u.x >> 16);
        int pos = atomicAdd(&cursor[r], 1);
        int2 pr; pr.x = (int)(u.x & 0xffffu); pr.y = (int)u.y;
        cpair[pos] = pr;
    }
}

// ---------------- SpMM (bf16 gather) + fused column stats; bf16 AGG out ----------------
__global__ __launch_bounds__(256) void spmm_fused_k(const int* __restrict__ rowptr,
    const int2* __restrict__ cpair, const ushort* __restrict__ H,
    ushort* __restrict__ AGG, float* __restrict__ psum, float* __restrict__ psq, int n)
{
    const int t = threadIdx.x;
    const int gid = blockIdx.x * 256 + t;
    const int r = gid >> 4;
    const int q = t & 15;
    float a[8];
    #pragma unroll
    for (int j = 0; j < 8; j++) a[j] = 0.f;

    if (r < n) {
        int p0 = rowptr[r], p1 = rowptr[r + 1];
        const ushort* Hq = H + q * 8;
        for (int p = p0; p < p1; p++) {
            int2 cv = cpair[p];
            float v = __int_as_float(cv.y);
            uint4 u = *reinterpret_cast<const uint4*>(Hq + (size_t)cv.x * DD);
            a[0] = fmaf(v, __uint_as_float(u.x << 16), a[0]);
            a[1] = fmaf(v, __uint_as_float(u.x & 0xffff0000u), a[1]);
            a[2] = fmaf(v, __uint_as_float(u.y << 16), a[2]);
            a[3] = fmaf(v, __uint_as_float(u.y & 0xffff0000u), a[3]);
            a[4] = fmaf(v, __uint_as_float(u.z << 16), a[4]);
            a[5] = fmaf(v, __uint_as_float(u.z & 0xffff0000u), a[5]);
            a[6] = fmaf(v, __uint_as_float(u.w << 16), a[6]);
            a[7] = fmaf(v, __uint_as_float(u.w & 0xffff0000u), a[7]);
        }
        *reinterpret_cast<uint4*>(AGG + (size_t)r * DD + q * 8) = bf8_pack(a);
    }

    // column stats: reduce 4 rows within wave, 4 waves via LDS, atomic into 64 slots
    float s[8], sq[8];
    #pragma unroll
    for (int j = 0; j < 8; j++) { s[j] = a[j]; sq[j] = a[j] * a[j]; }
    #pragma unroll
    for (int j = 0; j < 8; j++) {
        s[j]  += __shfl_xor(s[j], 16);  sq[j] += __shfl_xor(sq[j], 16);
        s[j]  += __shfl_xor(s[j], 32);  sq[j] += __shfl_xor(sq[j], 32);
    }
    __shared__ float sA[4][DD], qA[4][DD];
    const int wave = t >> 6, lane = t & 63;
    if (lane < 16) {
        #pragma unroll
        for (int j = 0; j < 8; j++) {
            sA[wave][lane * 8 + j] = s[j];
            qA[wave][lane * 8 + j] = sq[j];
        }
    }
    __syncthreads();
    if (t < DD) {
        float S = 0.f, Q = 0.f;
        #pragma unroll
        for (int w = 0; w < 4; w++) { S += sA[w][t]; Q += qA[w][t]; }
        int slot = (blockIdx.x & 63) * DD + t;
        atomicAdd(&psum[slot], S);
        atomicAdd(&psq[slot], Q);
    }
}

extern "C" void kernel_launch(void* const* d_in, const int* in_sizes, int n_in,
                              void* d_out, int out_size, void* d_ws, size_t ws_size,
                              hipStream_t stream)
{
    const float* x_in     = (const float*)d_in[0];
    const int*   erow     = (const int*)d_in[1];
    const int*   ecol     = (const int*)d_in[2];
    const float* evalv    = (const float*)d_in[3];
    const float* gamma    = (const float*)d_in[4];
    const float* beta     = (const float*)d_in[5];
    const float* fc_in_w  = (const float*)d_in[6];
    const float* fc_in_b  = (const float*)d_in[7];
    const float* gc_w     = (const float*)d_in[8];
    // d_in[9] = gc_b: no-op under PairNorm (column-mean subtraction cancels it)
    const float* fc_out_w = (const float*)d_in[10];
    const float* fc_out_b = (const float*)d_in[11];
    float* out = (float*)d_out;

    const int n = in_sizes[0] / DD;   // 50000
    const int e = in_sizes[1];        // 800000
    const int NB = 512;
    const int nscan = (n + SCAN_TILE - 1) / SCAN_TILE;
    const int nbuk = (n + (1 << BSH) - 1) >> BSH;   // 98

    char* w = (char*)d_ws;
    ushort* X     = (ushort*)w;  w += (size_t)n * DD * 2;      // residual stream bf16
    ushort* Hb    = (ushort*)w;  w += (size_t)n * DD * 2;
    ushort* AGG   = (ushort*)w;  w += (size_t)n * DD * 2;
    float* PSUM   = (float*)w;   w += (size_t)NB * DD * 4;
    float* PSQ    = (float*)w;   w += (size_t)NB * DD * 4;
    float* PSUMS  = (float*)w;   w += (size_t)64 * DD * 4;
    float* PSQS   = (float*)w;   w += (size_t)64 * DD * 4;
    float* AB     = (float*)w;   w += 2 * DD * 4;
    ushort* Wt    = (ushort*)w;  w += (size_t)4 * DD * DD * 2;
    ushort* Wtc   = (ushort*)w;  w += (size_t)DD * DD * 2;
    ushort* WtO   = (ushort*)w;  w += (size_t)48 * DD * 2;
    float* Ycomp  = (float*)w;   w += (size_t)DD * DD * 4;
    float* bc     = (float*)w;   w += DD * 4;
    int* deg      = (int*)w;     w += (size_t)(n + 4) * 4;
    int* rowptr   = (int*)w;     w += (size_t)(n + 4) * 4;
    int* cursor   = (int*)w;     w += (size_t)(n + 4) * 4;
    int* slocal   = (int*)w;     w += (size_t)(n + 4) * 4;
    int* bsum     = (int*)w;     w += 1024;
    int* bpre     = (int*)w;     w += 1024;
    int* gcur     = (int*)w;     w += 1024;
    uint2* binned = (uint2*)w;   w += (size_t)e * 8;
    int2* cpair   = (int2*)w;    w += (size_t)e * 8;

    // ---- CSR build: hist -> scan -> binned 2-pass scatter ----
    hipMemsetAsync(deg, 0, (size_t)n * 4, stream);
    hist_k<<<(e + 255) / 256, 256, 0, stream>>>(erow, deg, e);
    scan1_k<<<nscan, 256, 0, stream>>>(deg, slocal, bsum, n);
    scan2_k<<<1, 256, 0, stream>>>(bsum, bpre, nscan, rowptr, n);
    scan3_k<<<nscan, 256, 0, stream>>>(slocal, bpre, rowptr, cursor, n);
    gcur_init_k<<<1, 128, 0, stream>>>(rowptr, gcur, n, nbuk);
    bin_a_k<<<(e + 2047) / 2048, 256, 0, stream>>>(erow, ecol, evalv, gcur, binned, e);
    bin_b_k<<<nbuk, 256, 0, stream>>>(binned, rowptr, cursor, cpair, n);

    // ---- weights ----
    wtrans_k<<<64, 256, 0, stream>>>(gc_w, Wt);
    gemm_mfma_k<0, 8, 128, false, false, false><<<2, 256, 0, stream>>>(
        fc_in_w, Wt, nullptr, nullptr, nullptr, Ycomp, DD, DD);          // Ycomp = W_in @ W0
    wtrans_k<<<16, 256, 0, stream>>>(Ycomp, Wtc);
    bias_comp_k<<<1, 128, 0, stream>>>(fc_in_b, gc_w, bc);               // bc = b @ W0
    wtrans_out_k<<<1, 256, 0, stream>>>(fc_out_w, WtO);

    // ---- BN stats ----
    col_reduce_k<<<NB, 256, 0, stream>>>(x_in, n, PSUM, PSQ);
    finalize_k<true><<<1, 1024, 0, stream>>>(PSUM, PSQ, NB, n, gamma, beta, AB);

    const int gblocks64 = (n + 63) / 64;
    const int sblocks = ((size_t)n * 16 + 255) / 256;

    // ---- layer 0: Hb = BN(x_in) @ (W_in@W0) + b@W0 ----
    gemm_mfma_k<1, 8, 128, true, true, false><<<gblocks64, 256, 0, stream>>>(
        x_in, Wtc, AB, bc, nullptr, Hb, DD, n);

    for (int l = 0; l < 4; l++) {
        hipMemsetAsync(PSUMS, 0, (size_t)2 * 64 * DD * 4, stream);
        spmm_fused_k<<<sblocks, 256, 0, stream>>>(rowptr, cpair, Hb, AGG, PSUMS, PSQS, n);
        finalize_k<false><<<1, 1024, 0, stream>>>(PSUMS, PSQS, 64, n, nullptr, nullptr, AB);
        if (l < 3) {
            if (l == 0)
                gemm_mfma_k<2, 8, 128, false, true, true><<<gblocks64, 256, 0, stream>>>(
                    AGG, Wt + (size_t)(l + 1) * DD * DD, AB, nullptr, X, Hb, DD, n);
            else
                gemm_mfma_k<3, 8, 128, false, true, true><<<gblocks64, 256, 0, stream>>>(
                    AGG, Wt + (size_t)(l + 1) * DD * DD, AB, nullptr, X, Hb, DD, n);
        } else {
            gemm_mfma_k<3, 3, 40, true, false, false><<<gblocks64, 256, 0, stream>>>(
                AGG, WtO, AB, fc_out_b, X, out, 40, n);
        }
    }
}

// Round 8
// 386.984 us; speedup vs baseline: 11.4254x; 1.0832x over previous
//
#include <hip/hip_runtime.h>
#include <hip/hip_bf16.h>

// DeepGCN forward, restructured:
//   CSR build (histogram -> 3-phase scan -> 2-pass BINNED scatter) -> BN stats ->
//   L0 GEMM from x_in with composite weight (W_in@W0) + composite bias (b@W0) ->
//   4x [ spmm(bf16 gather + fused column stats, bf16 AGG out) -> finalize(PN) ->
//        next GEMM with fused PN+ReLU+residual pre-stage (bf16 X stream) ] ->
//   fc_out MFMA (48-col padded), fused with final PN+ReLU+residual.
// R5: paired scatter, spmm-stats fusion, PN fusion, fc_in elimination.
// R6: binned 2-pass scatter, AGG+X bf16.
// R7: spmm 8/4-deep manual MLP unroll (was latency-bound: dependent cpair->gather
//     chain, ~1 outstanding gather/thread, VALUBusy 20%).

constexpr int DD = 128;

struct alignas(16) f4 { float v[4]; };
typedef unsigned short ushort;
typedef unsigned int uint;
typedef short short8 __attribute__((ext_vector_type(8)));
typedef float f32x4 __attribute__((ext_vector_type(4)));

__device__ inline ushort f2bf(float f) {   // RNE f32->bf16
    uint u = __float_as_uint(f);
    u += 0x7fffu + ((u >> 16) & 1u);
    return (ushort)(u >> 16);
}
__device__ inline void bf8_unpack(uint4 u, float* v) {
    v[0] = __uint_as_float(u.x << 16); v[1] = __uint_as_float(u.x & 0xffff0000u);
    v[2] = __uint_as_float(u.y << 16); v[3] = __uint_as_float(u.y & 0xffff0000u);
    v[4] = __uint_as_float(u.z << 16); v[5] = __uint_as_float(u.z & 0xffff0000u);
    v[6] = __uint_as_float(u.w << 16); v[7] = __uint_as_float(u.w & 0xffff0000u);
}
__device__ inline uint4 bf8_pack(const float* v) {
    uint4 o;
    o.x = (uint)f2bf(v[0]) | ((uint)f2bf(v[1]) << 16);
    o.y = (uint)f2bf(v[2]) | ((uint)f2bf(v[3]) << 16);
    o.z = (uint)f2bf(v[4]) | ((uint)f2bf(v[5]) << 16);
    o.w = (uint)f2bf(v[6]) | ((uint)f2bf(v[7]) << 16);
    return o;
}

// ---------------- column reduce (BN stats over x_in) ----------------
__global__ __launch_bounds__(256) void col_reduce_k(const float* __restrict__ X, int n,
    float* __restrict__ psum, float* __restrict__ psq)
{
    int c = threadIdx.x & (DD - 1);
    int half = threadIdx.x >> 7;
    int rows_per_blk = (n + gridDim.x - 1) / gridDim.x;
    int r0 = blockIdx.x * rows_per_blk;
    int r1 = min(n, r0 + rows_per_blk);
    float s = 0.f, ss = 0.f;
    for (int r = r0 + half; r < r1; r += 2) {
        float v = X[(size_t)r * DD + c];
        s += v; ss += v * v;
    }
    __shared__ float ls[256], lq[256];
    ls[threadIdx.x] = s; lq[threadIdx.x] = ss;
    __syncthreads();
    if (half == 0) {
        psum[blockIdx.x * DD + c] = ls[c] + ls[c + 128];
        psq [blockIdx.x * DD + c] = lq[c] + lq[c + 128];
    }
}

// ---------------- finalize (BN or PN) ----------------
template<bool BN>
__global__ __launch_bounds__(1024) void finalize_k(const float* __restrict__ psum,
    const float* __restrict__ psq, int nblk, int n,
    const float* __restrict__ gamma, const float* __restrict__ beta,
    float* __restrict__ AB)
{
    const int c = threadIdx.x & (DD - 1);
    const int g = threadIdx.x >> 7;   // 0..7
    float s = 0.f, ss = 0.f;
    for (int b = g; b < nblk; b += 8) {
        s  += psum[b * DD + c];
        ss += psq [b * DD + c];
    }
    __shared__ float Ls[8][DD], Lq[8][DD];
    Ls[g][c] = s; Lq[g][c] = ss;
    __syncthreads();
    float ts = 0.f, tss = 0.f;
    #pragma unroll
    for (int k = 0; k < 8; k++) { ts += Ls[k][c]; tss += Lq[k][c]; }
    float mu = ts / (float)n;
    if (BN) {
        if (threadIdx.x < DD) {
            float var = tss / (float)n - mu * mu;
            float a = gamma[c] * rsqrtf(var + 1e-5f);
            AB[c] = a;
            AB[DD + c] = beta[c] - mu * a;
        }
    } else {
        float cent = tss - (float)n * mu * mu;
        __syncthreads();
        if (g == 0) Ls[0][c] = cent;
        __syncthreads();
        for (int off = 64; off > 0; off >>= 1) {
            if (threadIdx.x < off) Ls[0][threadIdx.x] += Ls[0][threadIdx.x + off];
            __syncthreads();
        }
        if (threadIdx.x < DD) {
            float inv = rsqrtf(1e-6f + Ls[0][0] / (float)n);
            AB[c] = inv;
            AB[DD + c] = -mu * inv;
        }
    }
}

// ---------------- weight transpose 128x128: Wt[n][k] = bf16(W[k][n]) ----------------
__global__ __launch_bounds__(256) void wtrans_k(const float* __restrict__ Wsrc,
    ushort* __restrict__ Wt)
{
    int b = blockIdx.x;
    int w = b >> 4, tile = b & 15;
    int tr = (tile >> 2) * 32, tc = (tile & 3) * 32;
    const float* W = Wsrc + (size_t)w * DD * DD;
    ushort* Wo = Wt + (size_t)w * DD * DD;
    __shared__ float tls[32][33];
    int tx = threadIdx.x & 31, ty = threadIdx.x >> 5;  // 32 x 8
    #pragma unroll
    for (int j = 0; j < 32; j += 8)
        tls[ty + j][tx] = W[(size_t)(tr + ty + j) * DD + tc + tx];
    __syncthreads();
    #pragma unroll
    for (int j = 0; j < 32; j += 8)
        Wo[(size_t)(tc + ty + j) * DD + (tr + tx)] = f2bf(tls[tx][ty + j]);
}

// ---------------- fc_out weight: [128][40] f32 -> [48][128] bf16 (zero-padded) ------
__global__ __launch_bounds__(256) void wtrans_out_k(const float* __restrict__ W,
    ushort* __restrict__ Wt)
{
    for (int i = threadIdx.x; i < 48 * DD; i += 256) {
        int nn = i >> 7, k = i & 127;
        float v = (nn < 40) ? W[(size_t)k * 40 + nn] : 0.f;
        Wt[i] = f2bf(v);
    }
}

// ---------------- composite bias: bc[n] = sum_j b[j] * W0[j][n] ----------------
__global__ __launch_bounds__(128) void bias_comp_k(const float* __restrict__ b,
    const float* __restrict__ W0, float* __restrict__ bc)
{
    int nn = threadIdx.x;
    float acc = 0.f;
    for (int j = 0; j < DD; j++) acc += b[j] * W0[(size_t)j * DD + nn];
    bc[nn] = acc;
}

// ---------------- MFMA GEMM with fused pre-stage ----------------
// PRE: 0=f32 plain, 1=f32 BN affine, 2=bf16-in PN relu(x*A+B), 3=PN + residual (bf16 X)
// NCOLF: #16-col fragments (8 -> 128 cols, 3 -> 48 padded for 40)
// WRITEX: write pre-staged x (bf16) back to Xres residual stream
template<int PRE, int NCOLF, int NCOLW, bool BIAS, bool OUTBF, bool WRITEX>
__global__ __launch_bounds__(256) void gemm_mfma_k(const void* __restrict__ INv,
    const ushort* __restrict__ Wt, const float* __restrict__ AB,
    const float* __restrict__ bias, void* __restrict__ Xresv,
    void* __restrict__ Yout, int ystride, int n)
{
    __shared__ short xs[64][136];            // [m][k] bf16 (pad 136)
    __shared__ short ws[NCOLF * 16][136];    // [n][k] bf16
    __shared__ float bias_s[DD];
    const int t = threadIdx.x;
    if (BIAS && t < NCOLW) bias_s[t] = bias[t];

    const int row0 = blockIdx.x * 64;
    if (PRE <= 1) {
        const float* IN = (const float*)INv;
        for (int i = t; i < 64 * 32; i += 256) {
            int m = i >> 5, koff = (i & 31) << 2;
            int r = row0 + m;
            f4 v; v.v[0] = v.v[1] = v.v[2] = v.v[3] = 0.f;
            if (r < n) {
                v = *reinterpret_cast<const f4*>(IN + (size_t)r * DD + koff);
                if (PRE == 1) {
                    #pragma unroll
                    for (int j = 0; j < 4; j++) v.v[j] = v.v[j] * AB[koff + j] + AB[DD + koff + j];
                }
            }
            uint2 p;
            p.x = (uint)f2bf(v.v[0]) | ((uint)f2bf(v.v[1]) << 16);
            p.y = (uint)f2bf(v.v[2]) | ((uint)f2bf(v.v[3]) << 16);
            *reinterpret_cast<uint2*>(&xs[m][koff]) = p;
        }
    } else {
        const ushort* IN = (const ushort*)INv;
        ushort* Xres = (ushort*)Xresv;
        for (int i = t; i < 64 * 16; i += 256) {
            int m = i >> 4, k8 = (i & 15) << 3;
            int r = row0 + m;
            float v[8];
            if (r < n) {
                uint4 u = *reinterpret_cast<const uint4*>(IN + (size_t)r * DD + k8);
                bf8_unpack(u, v);
                #pragma unroll
                for (int j = 0; j < 8; j++)
                    v[j] = fmaxf(v[j] * AB[k8 + j] + AB[DD + k8 + j], 0.f);
                if (PRE == 3) {
                    uint4 xo = *reinterpret_cast<const uint4*>(Xres + (size_t)r * DD + k8);
                    float xov[8]; bf8_unpack(xo, xov);
                    #pragma unroll
                    for (int j = 0; j < 8; j++) v[j] += xov[j];
                }
                uint4 pk = bf8_pack(v);
                if (WRITEX)
                    *reinterpret_cast<uint4*>(Xres + (size_t)r * DD + k8) = pk;
                *reinterpret_cast<uint4*>(&xs[m][k8]) = pk;
            } else {
                uint4 z; z.x = z.y = z.z = z.w = 0u;
                *reinterpret_cast<uint4*>(&xs[m][k8]) = z;
            }
        }
    }
    // stage Wt
    for (int i = t; i < NCOLF * 256; i += 256) {
        int nn = i >> 4, koff = (i & 15) << 3;
        *reinterpret_cast<uint4*>(&ws[nn][koff]) =
            *reinterpret_cast<const uint4*>(Wt + (size_t)nn * DD + koff);
    }
    __syncthreads();

    const int wave = t >> 6, lane = t & 63, fr = lane & 15, g = lane >> 4;
    f32x4 acc[NCOLF];
    #pragma unroll
    for (int c = 0; c < NCOLF; c++) acc[c] = (f32x4){0.f, 0.f, 0.f, 0.f};

    #pragma unroll 2
    for (int ks = 0; ks < 4; ks++) {
        int k0 = ks * 32 + g * 8;
        short8 a = *reinterpret_cast<const short8*>(&xs[wave * 16 + fr][k0]);
        #pragma unroll
        for (int c = 0; c < NCOLF; c++) {
            short8 b = *reinterpret_cast<const short8*>(&ws[c * 16 + fr][k0]);
            // mfma(W_frag, X_frag): out lane&15 = X-row (m), g*4+reg = W-col (n)
            acc[c] = __builtin_amdgcn_mfma_f32_16x16x32_bf16(b, a, acc[c], 0, 0, 0);
        }
    }

    const int row = row0 + wave * 16 + fr;
    if (row < n) {
        #pragma unroll
        for (int c = 0; c < NCOLF; c++) {
            int n0 = c * 16 + g * 4;
            if (OUTBF) {
                float b0 = BIAS ? bias_s[n0 + 0] : 0.f, b1 = BIAS ? bias_s[n0 + 1] : 0.f;
                float b2 = BIAS ? bias_s[n0 + 2] : 0.f, b3 = BIAS ? bias_s[n0 + 3] : 0.f;
                uint2 o;
                o.x = (uint)f2bf(acc[c][0] + b0) | ((uint)f2bf(acc[c][1] + b1) << 16);
                o.y = (uint)f2bf(acc[c][2] + b2) | ((uint)f2bf(acc[c][3] + b3) << 16);
                *reinterpret_cast<uint2*>((ushort*)Yout + (size_t)row * DD + n0) = o;
            } else if (n0 + 3 < NCOLW) {
                f4 o;
                #pragma unroll
                for (int j = 0; j < 4; j++)
                    o.v[j] = acc[c][j] + (BIAS ? bias_s[n0 + j] : 0.f);
                *reinterpret_cast<f4*>((float*)Yout + (size_t)row * ystride + n0) = o;
            }
        }
    }
}

// ---------------- CSR build ----------------
__global__ __launch_bounds__(256) void hist_k(const int* __restrict__ erow,
    int* __restrict__ deg, int e)
{
    int i = blockIdx.x * 256 + threadIdx.x;
    if (i < e) atomicAdd(&deg[erow[i]], 1);
}

constexpr int SCAN_TILE = 1024;
constexpr int BSH = 9;                 // 512-row buckets

__global__ __launch_bounds__(256) void scan1_k(const int* __restrict__ deg,
    int* __restrict__ local, int* __restrict__ bsum, int n)
{
    const int t = threadIdx.x;
    const int base = blockIdx.x * SCAN_TILE + t * 4;
    int v0 = 0, v1 = 0, v2 = 0, v3 = 0;
    if (base + 3 < n) {
        int4 v = *reinterpret_cast<const int4*>(deg + base);
        v0 = v.x; v1 = v.y; v2 = v.z; v3 = v.w;
    } else {
        if (base + 0 < n) v0 = deg[base + 0];
        if (base + 1 < n) v1 = deg[base + 1];
        if (base + 2 < n) v2 = deg[base + 2];
        if (base + 3 < n) v3 = deg[base + 3];
    }
    int s = v0 + v1 + v2 + v3;
    __shared__ int ps[256];
    ps[t] = s;
    __syncthreads();
    for (int off = 1; off < 256; off <<= 1) {
        int add = (t >= off) ? ps[t - off] : 0;
        __syncthreads();
        ps[t] += add;
        __syncthreads();
    }
    int excl = (t > 0) ? ps[t - 1] : 0;
    int o0 = excl, o1 = excl + v0, o2 = o1 + v1, o3 = o2 + v2;
    if (base + 3 < n) {
        int4 o; o.x = o0; o.y = o1; o.z = o2; o.w = o3;
        *reinterpret_cast<int4*>(local + base) = o;
    } else {
        if (base + 0 < n) local[base + 0] = o0;
        if (base + 1 < n) local[base + 1] = o1;
        if (base + 2 < n) local[base + 2] = o2;
        if (base + 3 < n) local[base + 3] = o3;
    }
    if (t == 255) bsum[blockIdx.x] = ps[255];
}

__global__ __launch_bounds__(256) void scan2_k(const int* __restrict__ bsum,
    int* __restrict__ bpre, int nb, int* __restrict__ rowptr, int n)
{
    const int t = threadIdx.x;
    __shared__ int ps[256];
    ps[t] = (t < nb) ? bsum[t] : 0;
    __syncthreads();
    for (int off = 1; off < 256; off <<= 1) {
        int add = (t >= off) ? ps[t - off] : 0;
        __syncthreads();
        ps[t] += add;
        __syncthreads();
    }
    if (t < nb) bpre[t] = (t > 0) ? ps[t - 1] : 0;
    if (t == 255) rowptr[n] = ps[255];
}

__global__ __launch_bounds__(256) void scan3_k(const int* __restrict__ local,
    const int* __restrict__ bpre, int* __restrict__ rowptr, int* __restrict__ cursor, int n)
{
    const int base = blockIdx.x * SCAN_TILE + threadIdx.x * 4;
    const int p = bpre[blockIdx.x];
    if (base + 3 < n) {
        int4 v = *reinterpret_cast<const int4*>(local + base);
        v.x += p; v.y += p; v.z += p; v.w += p;
        *reinterpret_cast<int4*>(rowptr + base) = v;
        *reinterpret_cast<int4*>(cursor + base) = v;
    } else {
        #pragma unroll
        for (int j = 0; j < 4; j++)
            if (base + j < n) {
                int v = local[base + j] + p;
                rowptr[base + j] = v;
                cursor[base + j] = v;
            }
    }
}

// gcur[b] = start of bucket b's region in the edge array
__global__ void gcur_init_k(const int* __restrict__ rowptr, int* __restrict__ gcur,
    int n, int nbuk)
{
    int b = threadIdx.x;
    if (b <= nbuk) gcur[b] = rowptr[min(b << BSH, n)];
}

// pass A: bin edges by 512-row bucket (LDS rank; bucket-contiguous 8B writes)
__global__ __launch_bounds__(256) void bin_a_k(const int* __restrict__ erow,
    const int* __restrict__ ecol, const float* __restrict__ evalv,
    int* __restrict__ gcur, uint2* __restrict__ binned, int e)
{
    __shared__ int cnt[128];
    __shared__ int base[128];
    const int t = threadIdx.x;
    if (t < 128) cnt[t] = 0;
    __syncthreads();
    const int i0 = blockIdx.x * 2048 + t * 8;
    int rw[8], cl[8], rk[8];
    float vl[8];
    #pragma unroll
    for (int j = 0; j < 8; j++) {
        int idx = i0 + j;
        if (idx < e) { rw[j] = erow[idx]; cl[j] = ecol[idx]; vl[j] = evalv[idx]; }
        else rw[j] = -1;
    }
    #pragma unroll
    for (int j = 0; j < 8; j++)
        if (rw[j] >= 0) rk[j] = atomicAdd(&cnt[rw[j] >> BSH], 1);
    __syncthreads();
    if (t < 128) base[t] = cnt[t] ? atomicAdd(&gcur[t], cnt[t]) : 0;
    __syncthreads();
    #pragma unroll
    for (int j = 0; j < 8; j++) {
        if (rw[j] >= 0) {
            int b = rw[j] >> BSH, rl = rw[j] & ((1 << BSH) - 1);
            uint2 pr;
            pr.x = (uint)cl[j] | ((uint)rl << 16);
            pr.y = __float_as_uint(vl[j]);
            binned[base[b] + rk[j]] = pr;
        }
    }
}

// pass B: within-bucket scatter to CSR position (dest region ~64KB -> L2-resident)
__global__ __launch_bounds__(256) void bin_b_k(const uint2* __restrict__ binned,
    const int* __restrict__ rowptr, int* __restrict__ cursor,
    int2* __restrict__ cpair, int n)
{
    const int b = blockIdx.x;
    const int r0 = min(b << BSH, n), r1 = min((b + 1) << BSH, n);
    const int p0 = rowptr[r0], p1 = rowptr[r1];
    for (int p = p0 + threadIdx.x; p < p1; p += 256) {
        uint2 u = binned[p];
        int r = (b << BSH) + (int)(u.x >> 16);
        int pos = atomicAdd(&cursor[r], 1);
        int2 pr; pr.x = (int)(u.x & 0xffffu); pr.y = (int)u.y;
        cpair[pos] = pr;
    }
}

// ---------------- SpMM (bf16 gather) + fused column stats; bf16 AGG out ----------------
// R7: 8/4-deep manual MLP pipeline (descriptor loads batched, gathers batched).
__global__ __launch_bounds__(256) void spmm_fused_k(const int* __restrict__ rowptr,
    const int2* __restrict__ cpair, const ushort* __restrict__ H,
    ushort* __restrict__ AGG, float* __restrict__ psum, float* __restrict__ psq, int n)
{
    const int t = threadIdx.x;
    const int gid = blockIdx.x * 256 + t;
    const int r = gid >> 4;
    const int q = t & 15;
    float a[8];
    #pragma unroll
    for (int j = 0; j < 8; j++) a[j] = 0.f;

    if (r < n) {
        int p0 = rowptr[r], p1 = rowptr[r + 1];
        const ushort* Hq = H + q * 8;
        int p = p0;
        // 8-deep pipelined main loop
        for (; p + 8 <= p1; p += 8) {
            int2 c[8];
            #pragma unroll
            for (int j = 0; j < 8; j++) c[j] = cpair[p + j];
            uint4 u[8];
            #pragma unroll
            for (int j = 0; j < 8; j++)
                u[j] = *reinterpret_cast<const uint4*>(Hq + (size_t)c[j].x * DD);
            #pragma unroll
            for (int j = 0; j < 8; j++) {
                float v = __int_as_float(c[j].y);
                a[0] = fmaf(v, __uint_as_float(u[j].x << 16), a[0]);
                a[1] = fmaf(v, __uint_as_float(u[j].x & 0xffff0000u), a[1]);
                a[2] = fmaf(v, __uint_as_float(u[j].y << 16), a[2]);
                a[3] = fmaf(v, __uint_as_float(u[j].y & 0xffff0000u), a[3]);
                a[4] = fmaf(v, __uint_as_float(u[j].z << 16), a[4]);
                a[5] = fmaf(v, __uint_as_float(u[j].z & 0xffff0000u), a[5]);
                a[6] = fmaf(v, __uint_as_float(u[j].w << 16), a[6]);
                a[7] = fmaf(v, __uint_as_float(u[j].w & 0xffff0000u), a[7]);
            }
        }
        // 4-deep
        if (p + 4 <= p1) {
            int2 c[4];
            #pragma unroll
            for (int j = 0; j < 4; j++) c[j] = cpair[p + j];
            uint4 u[4];
            #pragma unroll
            for (int j = 0; j < 4; j++)
                u[j] = *reinterpret_cast<const uint4*>(Hq + (size_t)c[j].x * DD);
            #pragma unroll
            for (int j = 0; j < 4; j++) {
                float v = __int_as_float(c[j].y);
                a[0] = fmaf(v, __uint_as_float(u[j].x << 16), a[0]);
                a[1] = fmaf(v, __uint_as_float(u[j].x & 0xffff0000u), a[1]);
                a[2] = fmaf(v, __uint_as_float(u[j].y << 16), a[2]);
                a[3] = fmaf(v, __uint_as_float(u[j].y & 0xffff0000u), a[3]);
                a[4] = fmaf(v, __uint_as_float(u[j].z << 16), a[4]);
                a[5] = fmaf(v, __uint_as_float(u[j].z & 0xffff0000u), a[5]);
                a[6] = fmaf(v, __uint_as_float(u[j].w << 16), a[6]);
                a[7] = fmaf(v, __uint_as_float(u[j].w & 0xffff0000u), a[7]);
            }
            p += 4;
        }
        // scalar tail
        for (; p < p1; p++) {
            int2 cv = cpair[p];
            float v = __int_as_float(cv.y);
            uint4 u = *reinterpret_cast<const uint4*>(Hq + (size_t)cv.x * DD);
            a[0] = fmaf(v, __uint_as_float(u.x << 16), a[0]);
            a[1] = fmaf(v, __uint_as_float(u.x & 0xffff0000u), a[1]);
            a[2] = fmaf(v, __uint_as_float(u.y << 16), a[2]);
            a[3] = fmaf(v, __uint_as_float(u.y & 0xffff0000u), a[3]);
            a[4] = fmaf(v, __uint_as_float(u.z << 16), a[4]);
            a[5] = fmaf(v, __uint_as_float(u.z & 0xffff0000u), a[5]);
            a[6] = fmaf(v, __uint_as_float(u.w << 16), a[6]);
            a[7] = fmaf(v, __uint_as_float(u.w & 0xffff0000u), a[7]);
        }
        *reinterpret_cast<uint4*>(AGG + (size_t)r * DD + q * 8) = bf8_pack(a);
    }

    // column stats: reduce 4 rows within wave, 4 waves via LDS, atomic into 64 slots
    float s[8], sq[8];
    #pragma unroll
    for (int j = 0; j < 8; j++) { s[j] = a[j]; sq[j] = a[j] * a[j]; }
    #pragma unroll
    for (int j = 0; j < 8; j++) {
        s[j]  += __shfl_xor(s[j], 16);  sq[j] += __shfl_xor(sq[j], 16);
        s[j]  += __shfl_xor(s[j], 32);  sq[j] += __shfl_xor(sq[j], 32);
    }
    __shared__ float sA[4][DD], qA[4][DD];
    const int wave = t >> 6, lane = t & 63;
    if (lane < 16) {
        #pragma unroll
        for (int j = 0; j < 8; j++) {
            sA[wave][lane * 8 + j] = s[j];
            qA[wave][lane * 8 + j] = sq[j];
        }
    }
    __syncthreads();
    if (t < DD) {
        float S = 0.f, Q = 0.f;
        #pragma unroll
        for (int w = 0; w < 4; w++) { S += sA[w][t]; Q += qA[w][t]; }
        int slot = (blockIdx.x & 63) * DD + t;
        atomicAdd(&psum[slot], S);
        atomicAdd(&psq[slot], Q);
    }
}

extern "C" void kernel_launch(void* const* d_in, const int* in_sizes, int n_in,
                              void* d_out, int out_size, void* d_ws, size_t ws_size,
                              hipStream_t stream)
{
    const float* x_in     = (const float*)d_in[0];
    const int*   erow     = (const int*)d_in[1];
    const int*   ecol     = (const int*)d_in[2];
    const float* evalv    = (const float*)d_in[3];
    const float* gamma    = (const float*)d_in[4];
    const float* beta     = (const float*)d_in[5];
    const float* fc_in_w  = (const float*)d_in[6];
    const float* fc_in_b  = (const float*)d_in[7];
    const float* gc_w     = (const float*)d_in[8];
    // d_in[9] = gc_b: no-op under PairNorm (column-mean subtraction cancels it)
    const float* fc_out_w = (const float*)d_in[10];
    const float* fc_out_b = (const float*)d_in[11];
    float* out = (float*)d_out;

    const int n = in_sizes[0] / DD;   // 50000
    const int e = in_sizes[1];        // 800000
    const int NB = 512;
    const int nscan = (n + SCAN_TILE - 1) / SCAN_TILE;
    const int nbuk = (n + (1 << BSH) - 1) >> BSH;   // 98

    char* w = (char*)d_ws;
    ushort* X     = (ushort*)w;  w += (size_t)n * DD * 2;      // residual stream bf16
    ushort* Hb    = (ushort*)w;  w += (size_t)n * DD * 2;
    ushort* AGG   = (ushort*)w;  w += (size_t)n * DD * 2;
    float* PSUM   = (float*)w;   w += (size_t)NB * DD * 4;
    float* PSQ    = (float*)w;   w += (size_t)NB * DD * 4;
    float* PSUMS  = (float*)w;   w += (size_t)64 * DD * 4;
    float* PSQS   = (float*)w;   w += (size_t)64 * DD * 4;
    float* AB     = (float*)w;   w += 2 * DD * 4;
    ushort* Wt    = (ushort*)w;  w += (size_t)4 * DD * DD * 2;
    ushort* Wtc   = (ushort*)w;  w += (size_t)DD * DD * 2;
    ushort* WtO   = (ushort*)w;  w += (size_t)48 * DD * 2;
    float* Ycomp  = (float*)w;   w += (size_t)DD * DD * 4;
    float* bc     = (float*)w;   w += DD * 4;
    int* deg      = (int*)w;     w += (size_t)(n + 4) * 4;
    int* rowptr   = (int*)w;     w += (size_t)(n + 4) * 4;
    int* cursor   = (int*)w;     w += (size_t)(n + 4) * 4;
    int* slocal   = (int*)w;     w += (size_t)(n + 4) * 4;
    int* bsum     = (int*)w;     w += 1024;
    int* bpre     = (int*)w;     w += 1024;
    int* gcur     = (int*)w;     w += 1024;
    uint2* binned = (uint2*)w;   w += (size_t)e * 8;
    int2* cpair   = (int2*)w;    w += (size_t)e * 8;

    // ---- CSR build: hist -> scan -> binned 2-pass scatter ----
    hipMemsetAsync(deg, 0, (size_t)n * 4, stream);
    hist_k<<<(e + 255) / 256, 256, 0, stream>>>(erow, deg, e);
    scan1_k<<<nscan, 256, 0, stream>>>(deg, slocal, bsum, n);
    scan2_k<<<1, 256, 0, stream>>>(bsum, bpre, nscan, rowptr, n);
    scan3_k<<<nscan, 256, 0, stream>>>(slocal, bpre, rowptr, cursor, n);
    gcur_init_k<<<1, 128, 0, stream>>>(rowptr, gcur, n, nbuk);
    bin_a_k<<<(e + 2047) / 2048, 256, 0, stream>>>(erow, ecol, evalv, gcur, binned, e);
    bin_b_k<<<nbuk, 256, 0, stream>>>(binned, rowptr, cursor, cpair, n);

    // ---- weights ----
    wtrans_k<<<64, 256, 0, stream>>>(gc_w, Wt);
    gemm_mfma_k<0, 8, 128, false, false, false><<<2, 256, 0, stream>>>(
        fc_in_w, Wt, nullptr, nullptr, nullptr, Ycomp, DD, DD);          // Ycomp = W_in @ W0
    wtrans_k<<<16, 256, 0, stream>>>(Ycomp, Wtc);
    bias_comp_k<<<1, 128, 0, stream>>>(fc_in_b, gc_w, bc);               // bc = b @ W0
    wtrans_out_k<<<1, 256, 0, stream>>>(fc_out_w, WtO);

    // ---- BN stats ----
    col_reduce_k<<<NB, 256, 0, stream>>>(x_in, n, PSUM, PSQ);
    finalize_k<true><<<1, 1024, 0, stream>>>(PSUM, PSQ, NB, n, gamma, beta, AB);

    const int gblocks64 = (n + 63) / 64;
    const int sblocks = ((size_t)n * 16 + 255) / 256;

    // ---- layer 0: Hb = BN(x_in) @ (W_in@W0) + b@W0 ----
    gemm_mfma_k<1, 8, 128, true, true, false><<<gblocks64, 256, 0, stream>>>(
        x_in, Wtc, AB, bc, nullptr, Hb, DD, n);

    for (int l = 0; l < 4; l++) {
        hipMemsetAsync(PSUMS, 0, (size_t)2 * 64 * DD * 4, stream);
        spmm_fused_k<<<sblocks, 256, 0, stream>>>(rowptr, cpair, Hb, AGG, PSUMS, PSQS, n);
        finalize_k<false><<<1, 1024, 0, stream>>>(PSUMS, PSQS, 64, n, nullptr, nullptr, AB);
        if (l < 3) {
            if (l == 0)
                gemm_mfma_k<2, 8, 128, false, true, true><<<gblocks64, 256, 0, stream>>>(
                    AGG, Wt + (size_t)(l + 1) * DD * DD, AB, nullptr, X, Hb, DD, n);
            else
                gemm_mfma_k<3, 8, 128, false, true, true><<<gblocks64, 256, 0, stream>>>(
                    AGG, Wt + (size_t)(l + 1) * DD * DD, AB, nullptr, X, Hb, DD, n);
        } else {
            gemm_mfma_k<3, 3, 40, true, false, false><<<gblocks64, 256, 0, stream>>>(
                AGG, WtO, AB, fc_out_b, X, out, 40, n);
        }
    }
}